// Round 8
// baseline (3307.030 us; speedup 1.0000x reference)
//
#include <hip/hip_runtime.h>
#include <stdint.h>

// ---------------------------------------------------------------------------
// LSTM-VAE persistent kernel, MI355X (gfx950).  B=128, T=512, I=L=64, H=512,
// 100 decoder steps.  fp32 in/out; bf16 MFMA internal.
//
// 128 WGs = 8 batch-groups(g) x 16 hidden-slices(s), block=512 (8 waves).
// Slice owns 32 hidden dims = 128 interleaved gate rows [i0,f0,g0,o0,...];
// W_hh slice in 64 VGPRs/lane as MFMA B-fragments. Decoder folds x_hat via
// W_comb = W_hh_dec + W_ih_dec@W_out; x_hat tiles on wave 7 of slices 0-3.
//
// Round-16 (from green r14 = 1664us; r15 crashed): r15's two SAFE changes,
// with the crasher (issue-early/check-late async split) REMOVED.
//   * r15 crash diagnosis: issue_stage used "=v" (no early-clobber) on a
//     two-load asm block -> dest regs could overlap the 2nd load's address
//     operand -> wild address -> GPU fault.  Deeper: splitting issue/wait
//     across asm statements lets the compiler copy/reallocate in-flight
//     dest VGPRs (it thinks the value is final at the asm) -> returning
//     load corrupts unrelated registers.  Async split abandoned; staging
//     is r14's MONOLITHIC load+waitcnt with "=&v" early-clobber (proven).
//   * Per-wave direct publish: each wave shfl-packs its own 4 h-dims per
//     batch row and stores 16x 8B (dword-atomic) right after its cell
//     update -- no Ho tile, no wave-0 funnel, no pre-publish barrier.
//     Layout verified: wave wv owns global dims s*32+wv*4+{0..3}; store
//     byte offset s*64+wv*8 in the 1024B batch row (= consumer order).
//   * Double-buffered LDS tile Al[2]: round R stages into Al[R&1].  A wave
//     reaches round t+1's barrier only after finishing its round-t reads;
//     parity t&1 is next written in round t+2, after that barrier -> ONE
//     barrier per step, no read/write overlap.  Decoder x_hat reads the
//     h_d parity while next-round staging writes the opposite parity.
//   * Backoff sleeps capped at s_sleep(4) (r14's 20x-slow outlier
//     dispatches looked like DVFS clock-down; avoid deep sleeps).
//
// Sync: POLL-ON-DATA phase-bit protocol (r9/r10, verified on hardware).
// |h|<=1 so bit14 of every bf16 is 0.  Round R writes buf[R&1] with each
// bf16 XOR'd by (phase(R) ? 0x4000 : 0); phase alternates on every reuse
// of a buffer.  Consumers poll their own 32B chunk until EVERY bf16
// carries the round's phase bit (stores are dword-atomic; torn arrival
// keeps polling; stale phase is always the complement).  Overwrite
// safety: depth-2 transitive certification -- a wave publishes R+1 only
// after its WG's barrier for R, which certifies whole-group consumption
// of R-1 before hbuf[(R+1)&1] is overwritten.  Round 513 (h_dec0) is
// computed locally -> decoder rounds >=514 use the shifted phase formula.
// hbuf1 pre-filled 0x40 so round 1 cannot false-trigger.  Flags kept only
// for the one-shot fp32 z exchange.  All coherent ops are the proven
// `sc0 sc1` (LLC-served) path -- no sc0-only, no XCC gating.
// ---------------------------------------------------------------------------

typedef short short8 __attribute__((ext_vector_type(8)));
typedef float f32x4 __attribute__((ext_vector_type(4)));
typedef unsigned int u32x4 __attribute__((ext_vector_type(4)));
typedef unsigned int u32x2 __attribute__((ext_vector_type(2)));

#define WS_FLAGS  0           // 8 g x 16 s x 128 B (z exchange only)
#define WS_HBUF0  16384       // 128 KB
#define WS_HBUF1  147456      // 128 KB
#define WS_Z      278528      // 32 KB fp32
#define WS_BCOMB  311296      // 8 KB fp32
#define WS_WCOMB  319488      // 2 MB bf16
#define WS_SEQB   2416640     // 8 MB bf16 seq
#define WS_END    10805248
#define WS_ZERO   WS_HBUF1    // memset flags + hbuf0 (h0 = 0, phase 0)
#define HB1_SIZE  131072      // hbuf1: fill 0x40 (bit14=1, != phase 0)

#define AL_HALF   8320        // shorts per LDS tile buffer (16 rows x 520)

static __device__ __forceinline__ float b2f(unsigned short u) {
    return __builtin_bit_cast(float, (unsigned int)u << 16);
}
static __device__ __forceinline__ unsigned short f2b(float f) {
    unsigned int u = __builtin_bit_cast(unsigned int, f);
    unsigned int r = u + 0x7FFFu + ((u >> 16) & 1u);  // RNE
    return (unsigned short)(r >> 16);
}
static __device__ __forceinline__ float sigm(float x)  { return 1.0f / (1.0f + __expf(-x)); }
static __device__ __forceinline__ float tanhx(float x) { return 1.0f - 2.0f / (__expf(2.0f * x) + 1.0f); }

static __device__ __forceinline__ short8 cvt8(const float* p) {
    const float4 a = ((const float4*)p)[0];
    const float4 b = ((const float4*)p)[1];
    short8 r;
    r[0] = (short)f2b(a.x); r[1] = (short)f2b(a.y);
    r[2] = (short)f2b(a.z); r[3] = (short)f2b(a.w);
    r[4] = (short)f2b(b.x); r[5] = (short)f2b(b.y);
    r[6] = (short)f2b(b.z); r[7] = (short)f2b(b.w);
    return r;
}

// phase(R): encoder/VAE rounds 0..512: (R>>1)&1.  Round 513 skipped (local
// h_dec0).  Decoder rounds 514..613 shifted so every buffer reuse still
// alternates (buf0: 512(0),514(1),516(0)..; buf1: 511(1),515(0),517(1)..).
static __device__ __forceinline__ uint32_t phase_of(uint32_t R) {
    return (R <= 512u) ? ((R >> 1) & 1u)
                       : ((((R - 513u) >> 1) & 1u) ^ 1u);
}

// LDS bank swizzle for the Al tile: 16B unit u of a row is stored at
// alperm(u).  Bijective; spreads the 8 lanes that used to share a 4-bank
// group across all 8 groups.
static __device__ __forceinline__ int alperm(int u) { return u ^ ((u >> 3) & 7); }

// --- coherent (LLC-served, L1/L2-bypass) coalesced ops: sc0 sc1 ----------
static __device__ __forceinline__ void load2x16_cc(const void* p0, const void* p1,
                                                   u32x4& v0, u32x4& v1) {
    asm volatile("global_load_dwordx4 %0, %2, off sc0 sc1\n\t"
                 "global_load_dwordx4 %1, %3, off sc0 sc1\n\t"
                 "s_waitcnt vmcnt(0)"
                 : "=&v"(v0), "=&v"(v1) : "v"(p0), "v"(p1) : "memory");
}
static __device__ __forceinline__ void drain_vm() {
    asm volatile("s_waitcnt vmcnt(0)" ::: "memory");
}

// ---------------------------------------------------------------------------
// Prologue A: seq fp32 -> bf16
// ---------------------------------------------------------------------------
__global__ void __launch_bounds__(256)
seqcvt_kernel(const float* __restrict__ src, unsigned short* __restrict__ dst)
{
    int i = (blockIdx.x * 256 + threadIdx.x) * 4;
    float4 v = *(const float4*)(src + i);
    uint32_t lo = (uint32_t)f2b(v.x) | ((uint32_t)f2b(v.y) << 16);
    uint32_t hi = (uint32_t)f2b(v.z) | ((uint32_t)f2b(v.w) << 16);
    uint2 o; o.x = lo; o.y = hi;
    *(uint2*)(dst + i) = o;
}

// ---------------------------------------------------------------------------
// Prologue B: W_comb = W_hh_dec + W_ih_dec @ W_out (bf16 out), b_comb (fp32)
// ---------------------------------------------------------------------------
__global__ void __launch_bounds__(256)
wcomb_kernel(const float* __restrict__ Wih_d,
             const float* __restrict__ Whh_d,
             const float* __restrict__ Wout,
             const float* __restrict__ bih_d,
             const float* __restrict__ bhh_d,
             const float* __restrict__ bout,
             unsigned char* __restrict__ ws)
{
    __shared__ float Ash[64][64];
    __shared__ float Bsh[64][65];
    const int bid = blockIdx.x, t = threadIdx.x;
    const int gt0 = (bid >> 3) * 64, ht0 = (bid & 7) * 64;
    for (int j = 0; j < 16; ++j) {
        int idx = t + j * 256;
        int r = idx >> 6, c = idx & 63;
        Ash[r][c] = Wih_d[(size_t)(gt0 + r) * 64 + c];
        Bsh[r][c] = Wout[(size_t)r * 512 + ht0 + c];
    }
    __syncthreads();
    const int gl = t >> 2, hl0 = (t & 3) * 16;
    for (int hh = 0; hh < 16; ++hh) {
        float acc = 0.f;
        #pragma unroll
        for (int i = 0; i < 64; ++i) acc += Ash[gl][i] * Bsh[i][hl0 + hh];
        int g = gt0 + gl, h = ht0 + hl0 + hh;
        float v = Whh_d[(size_t)g * 512 + h] + acc;
        ((unsigned short*)(ws + WS_WCOMB))[(size_t)g * 512 + h] = f2b(v);
    }
    if ((bid & 7) == 0 && t < 64) {
        int g = gt0 + t;
        float acc = bih_d[g] + bhh_d[g];
        #pragma unroll
        for (int i = 0; i < 64; ++i) acc += bout[i] * Ash[t][i];
        ((float*)(ws + WS_BCOMB))[g] = acc;
    }
}

// ---------------------------------------------------------------------------
// Main persistent kernel
// ---------------------------------------------------------------------------
__global__ void __launch_bounds__(512, 2)
vae_persistent(const float* __restrict__ seq,
               const unsigned short* __restrict__ seqb,
               const float* __restrict__ eps,
               const float* __restrict__ Wih_e,
               const float* __restrict__ Whh_e,
               const float* __restrict__ bih_e,
               const float* __restrict__ bhh_e,
               const float* __restrict__ Wmean,
               const float* __restrict__ bmean,
               const float* __restrict__ Wlv,
               const float* __restrict__ blv,
               const float* __restrict__ Winit,
               const float* __restrict__ binit,
               const float* __restrict__ Whh_d,
               const float* __restrict__ bih_d,
               const float* __restrict__ bhh_d,
               const float* __restrict__ Wout,
               const float* __restrict__ bout,
               unsigned char* __restrict__ ws,
               float* __restrict__ out)
{
    __shared__ __align__(16) short Al[2 * AL_HALF];  // double-buffered h tile
    __shared__ float fbuf[128];                      // mean/logvar scratch
    __shared__ float zl[16 * 64];                    // z tile (fp32)

    const int tid  = threadIdx.x;
    const int g    = blockIdx.x & 7;        // batch group
    const int s    = blockIdx.x >> 3;       // hidden slice
    const int b0   = g * 16;
    const int lane = tid & 63;
    const int wv   = tid >> 6;
    const int col  = lane & 15;
    const int q    = lane >> 4;
    const int nloc = wv * 16 + col;
    const int gt   = nloc & 3;              // 0=i,1=f,2=g,3=o
    const int grow = gt * 512 + s * 32 + (nloc >> 2);

    uint32_t* flags = (uint32_t*)(ws + WS_FLAGS) + (size_t)g * 512;  // z only
    unsigned char* hbuf0 = ws + WS_HBUF0;
    unsigned char* hbuf1 = ws + WS_HBUF1;
    uint32_t* zbuf = (uint32_t*)(ws + WS_Z);

    float cst[4] = {0.f, 0.f, 0.f, 0.f};

    // Per-thread swizzled LDS offsets (all consumers fully unrolled -> VGPRs)
    int aoff[16];
    #pragma unroll
    for (int kt = 0; kt < 16; ++kt)
        aoff[kt] = col * 520 + alperm(kt * 4 + q) * 8;   // short index
    const int stg_b  = tid >> 5;                          // staged row
    const int stg_c  = tid & 31;                          // 32B chunk
    const int stg_u0 = alperm(stg_c * 2);                 // unit of first 16B
    // second 16B unit is stg_u0 ^ 1

    // ---- stage round R into Al[R&1]: monolithic one-shot + backoff poll --
    auto wait_and_stage = [&](uint32_t R) {
        const unsigned char* src = (R & 1) ? hbuf1 : hbuf0;
        const uint32_t pm = phase_of(R) ? 0x40004000u : 0u;
        const unsigned char* p0 = src + (size_t)(b0 + stg_b) * 1024 + stg_c * 32;
        u32x4 v0, v1;
        uint32_t tries = 0;
        for (;;) {
            load2x16_cc(p0, p0 + 16, v0, v1);
            uint32_t bad = 0;
            #pragma unroll
            for (int i = 0; i < 4; ++i) {
                bad |= (v0[i] & 0x40004000u) ^ pm;
                bad |= (v1[i] & 0x40004000u) ^ pm;
            }
            if (bad == 0) break;               // per-lane exit
            if (tries == 1)      __builtin_amdgcn_s_sleep(1);
            else if (tries == 2) __builtin_amdgcn_s_sleep(2);
            else if (tries >= 3) __builtin_amdgcn_s_sleep(4);  // capped (DVFS)
            ++tries;
        }
        #pragma unroll
        for (int i = 0; i < 4; ++i) { v0[i] ^= pm; v1[i] ^= pm; }
        u32x4* dst = (u32x4*)(Al + (R & 1) * AL_HALF);   // row stride 65 units
        dst[stg_b * 65 + stg_u0]       = v0;
        dst[stg_b * 65 + (stg_u0 ^ 1)] = v1;
        __syncthreads();                       // the ONE barrier per step
    };

    // ---- cell update + per-wave direct publish of round R ----------------
    // After the quad shfl-reduce all 4 lanes of a quad hold h for batch
    // row q*4+r, hidden dim wv*4+(col>>2).  Lane col==r in each q-group
    // packs dims wv*4+{0..3} (from cols 0,4,8,12) into 8B and stores it
    // (2 dword-atomic components) at row byte offset s*64 + wv*8.
    auto cell_publish = [&](f32x4 acc, uint32_t R) {
        float act[4];
        #pragma unroll
        for (int r = 0; r < 4; ++r)
            act[r] = (gt == 2) ? tanhx(acc[r]) : sigm(acc[r]);
        int base = lane & ~3;
        #pragma unroll
        for (int r = 0; r < 4; ++r) {
            float vi = __shfl(act[r], base + 0);
            float vf = __shfl(act[r], base + 1);
            float vg = __shfl(act[r], base + 2);
            float vo = __shfl(act[r], base + 3);
            cst[r] = vf * cst[r] + vi * vg;
            act[r] = vo * tanhx(cst[r]);
        }
        unsigned char* dst = (R & 1) ? hbuf1 : hbuf0;
        const uint32_t pm = phase_of(R) ? 0x40004000u : 0u;
        const int qb = lane & 48;
        #pragma unroll
        for (int r = 0; r < 4; ++r) {
            uint32_t u = (uint32_t)f2b(act[r]);
            uint32_t g0 = (uint32_t)__shfl((int)u, qb + 0);
            uint32_t g1 = (uint32_t)__shfl((int)u, qb + 4);
            uint32_t g2 = (uint32_t)__shfl((int)u, qb + 8);
            uint32_t g3 = (uint32_t)__shfl((int)u, qb + 12);
            if (col == r) {
                u32x2 pk;
                pk[0] = (g0 | (g1 << 16)) ^ pm;
                pk[1] = (g2 | (g3 << 16)) ^ pm;
                void* p = dst + (size_t)(b0 + q * 4 + r) * 1024 + s * 64 + wv * 8;
                asm volatile("global_store_dwordx2 %0, %1, off sc0 sc1"
                             :: "v"(p), "v"(pk) : "memory");
            }
        }
    };

    short8 wfrag[16];
    auto load_wfrag_f32 = [&](const float* Wsrc) {
        #pragma unroll
        for (int kt = 0; kt < 16; ++kt)
            wfrag[kt] = cvt8(Wsrc + (size_t)grow * 512 + kt * 32 + q * 8);
    };
    auto load_wfrag_bf16 = [&](const unsigned short* Wsrc) {
        #pragma unroll
        for (int kt = 0; kt < 16; ++kt)
            wfrag[kt] = *(const short8*)((const short*)Wsrc +
                         (size_t)grow * 512 + kt * 32 + q * 8);
    };

    // ---------------- encoder: 512 steps ----------------
    load_wfrag_f32(Whh_e);
    short8 xwf[2];
    #pragma unroll
    for (int kt = 0; kt < 2; ++kt)
        xwf[kt] = cvt8(Wih_e + (size_t)grow * 64 + kt * 32 + q * 8);
    const float bias_e = bih_e[grow] + bhh_e[grow];

    auto load_x = [&](int t, short8* xf) {
        if (seqb) {
            const short* xs = (const short*)seqb + ((size_t)(b0 + col) * 512 + t) * 64 + q * 8;
            xf[0] = *(const short8*)(xs);
            xf[1] = *(const short8*)(xs + 32);
        } else {
            const float* xs = seq + ((size_t)(b0 + col) * 512 + t) * 64 + q * 8;
            xf[0] = cvt8(xs);
            xf[1] = cvt8(xs + 32);
        }
    };

    short8 xf[2];
    load_x(0, xf);
    for (uint32_t t = 0; t < 512; ++t) {
        // x-part first: independent of Al, overlaps the poll
        f32x4 acc = {bias_e, bias_e, bias_e, bias_e};
        acc = __builtin_amdgcn_mfma_f32_16x16x32_bf16(xf[0], xwf[0], acc, 0, 0, 0);
        acc = __builtin_amdgcn_mfma_f32_16x16x32_bf16(xf[1], xwf[1], acc, 0, 0, 0);
        if (t < 511) load_x(t + 1, xf);
        wait_and_stage(t);                   // t=0: hbuf0 zeros, phase 0 -> instant
        const short* ab = Al + (t & 1) * AL_HALF;
        f32x4 acc1 = {0.f, 0.f, 0.f, 0.f};   // 2 chains: halve serial latency
        #pragma unroll
        for (int kt = 0; kt < 16; kt += 2) {
            short8 a0 = *(const short8*)(ab + aoff[kt]);
            short8 a1 = *(const short8*)(ab + aoff[kt + 1]);
            acc  = __builtin_amdgcn_mfma_f32_16x16x32_bf16(a0, wfrag[kt],     acc,  0, 0, 0);
            acc1 = __builtin_amdgcn_mfma_f32_16x16x32_bf16(a1, wfrag[kt + 1], acc1, 0, 0, 0);
        }
        #pragma unroll
        for (int r = 0; r < 4; ++r) acc[r] += acc1[r];
        cell_publish(acc, t + 1);            // per-wave direct stores, no barrier
    }

    // ---------------- VAE reparameterization (flag 513 = z ready) ---------
    wait_and_stage(512);                     // Al[0] = h_n
    if (tid < 128) {
        int which = tid >> 6, idx = tid & 63;
        int b = idx >> 2, ldl = idx & 3;
        int ld = s * 4 + ldl;
        const float* wrow = (which ? Wlv : Wmean) + (size_t)ld * 512;
        float a = (which ? blv[ld] : bmean[ld]);
        for (int u = 0; u < 64; ++u) {
            const short* ap = Al + b * 520 + alperm(u) * 8;   // parity-0 buffer
            const float* wp = wrow + u * 8;
            #pragma unroll
            for (int e = 0; e < 8; ++e)
                a += b2f((unsigned short)ap[e]) * wp[e];
        }
        out[819200 + which * 8192 + (size_t)(b0 + b) * 64 + ld] = a;
        fbuf[which * 64 + idx] = a;
    }
    __syncthreads();
    if (wv == 0) {
        int b = lane >> 2, ldl = lane & 3;
        int ld = s * 4 + ldl;
        float m = fbuf[lane], lv = fbuf[64 + lane];
        float e = eps[(size_t)(b0 + b) * 64 + ld];
        float z = m + e * __expf(0.5f * lv);
        __hip_atomic_store(zbuf + (size_t)(b0 + b) * 64 + ld,
                           __builtin_bit_cast(uint32_t, z),
                           __ATOMIC_RELAXED, __HIP_MEMORY_SCOPE_AGENT);
        drain_vm();
        if (lane == 0)
            __hip_atomic_store(&flags[s * 32], 513u,
                               __ATOMIC_RELAXED, __HIP_MEMORY_SCOPE_AGENT);
    }
    if (wv == 0 && lane < 16)
        while (__hip_atomic_load(&flags[lane * 32], __ATOMIC_RELAXED,
                                 __HIP_MEMORY_SCOPE_AGENT) < 513u) {}
    __syncthreads();

    // h_dec0 = z @ W_init^T + b_init -> Al[1] (round-513 parity, local)
    #pragma unroll
    for (int j = 0; j < 2; ++j) {
        int idx = tid + j * 512;
        int b = idx >> 6, l = idx & 63;
        uint32_t v = __hip_atomic_load(zbuf + (size_t)(b0 + b) * 64 + l,
                                       __ATOMIC_RELAXED, __HIP_MEMORY_SCOPE_AGENT);
        zl[b * 64 + l] = __builtin_bit_cast(float, v);
    }
    __syncthreads();
    {
        int b = tid >> 5, c = tid & 31;
        #pragma unroll
        for (int j = 0; j < 16; ++j) {
            int hd = c * 16 + j;
            float a = binit[hd];
            const float* wr = Winit + (size_t)hd * 64;
            #pragma unroll
            for (int l = 0; l < 64; ++l) a += zl[b * 64 + l] * wr[l];
            Al[AL_HALF + b * 520 + alperm(c * 2 + (j >> 3)) * 8 + (j & 7)] = (short)f2b(a);
        }
    }
    #pragma unroll
    for (int r = 0; r < 4; ++r) cst[r] = 0.f;
    __syncthreads();

    // -------- decoder: 100 steps; step d publishes h_{d+1} as R=514+d -----
    short8 wof[16];
    float xbias = 0.f;
    if (s < 4 && wv == 7) {                  // x_hat tile s on wave 7 (no duties)
        xbias = bout[s * 16 + col];
        #pragma unroll
        for (int kt = 0; kt < 16; ++kt)
            wof[kt] = cvt8(Wout + (size_t)(s * 16 + col) * 512 + kt * 32 + q * 8);
    }
    auto xhat_emit = [&](int d, const short* ab) {  // x_hat_d from ab (= h_{d+1})
        f32x4 a2 = {xbias, xbias, xbias, xbias};
        #pragma unroll
        for (int kt = 0; kt < 16; ++kt) {
            short8 a = *(const short8*)(ab + aoff[kt]);
            a2 = __builtin_amdgcn_mfma_f32_16x16x32_bf16(a, wof[kt], a2, 0, 0, 0);
        }
        #pragma unroll
        for (int r = 0; r < 4; ++r) {
            int b = q * 4 + r;
            out[((size_t)(b0 + b) * 100 + d) * 64 + s * 16 + col] = a2[r];
        }
    };

    load_wfrag_f32(Whh_d);                   // step 0: x0 == 0
    float bias = bih_d[grow] + bhh_d[grow];
    for (uint32_t d = 0; d < 100; ++d) {
        const uint32_t Rin = 513 + d;        // round holding h_d
        if (d > 0) wait_and_stage(Rin);      // Al[Rin&1] = h_d
        const short* ab = Al + (Rin & 1) * AL_HALF;
        f32x4 acc = {bias, bias, bias, bias};
        f32x4 acc1 = {0.f, 0.f, 0.f, 0.f};
        #pragma unroll
        for (int kt = 0; kt < 16; kt += 2) {
            short8 a0 = *(const short8*)(ab + aoff[kt]);
            short8 a1 = *(const short8*)(ab + aoff[kt + 1]);
            acc  = __builtin_amdgcn_mfma_f32_16x16x32_bf16(a0, wfrag[kt],     acc,  0, 0, 0);
            acc1 = __builtin_amdgcn_mfma_f32_16x16x32_bf16(a1, wfrag[kt + 1], acc1, 0, 0, 0);
        }
        #pragma unroll
        for (int r = 0; r < 4; ++r) acc[r] += acc1[r];
        cell_publish(acc, 514 + d);
        if (d >= 1 && s < 4 && wv == 7) xhat_emit(d - 1, ab);  // opposite parity
        if (d == 0) {                                          // vs next staging
            load_wfrag_bf16((const unsigned short*)(ws + WS_WCOMB));
            bias = ((const float*)(ws + WS_BCOMB))[grow];
        }
    }
    wait_and_stage(613);                     // Al[1] = h_100
    if (s < 4 && wv == 7) xhat_emit(99, Al + AL_HALF);
}

extern "C" void kernel_launch(void* const* d_in, const int* in_sizes, int n_in,
                              void* d_out, int out_size, void* d_ws, size_t ws_size,
                              hipStream_t stream) {
    (void)in_sizes; (void)n_in; (void)out_size;
    const float* seq   = (const float*)d_in[0];
    const float* eps   = (const float*)d_in[2];
    const float* Wih_e = (const float*)d_in[3];
    const float* Whh_e = (const float*)d_in[4];
    const float* bih_e = (const float*)d_in[5];
    const float* bhh_e = (const float*)d_in[6];
    const float* Wmean = (const float*)d_in[7];
    const float* bmean = (const float*)d_in[8];
    const float* Wlv   = (const float*)d_in[9];
    const float* blv   = (const float*)d_in[10];
    const float* Winit = (const float*)d_in[11];
    const float* binit = (const float*)d_in[12];
    const float* Wih_d = (const float*)d_in[13];
    const float* Whh_d = (const float*)d_in[14];
    const float* bih_d = (const float*)d_in[15];
    const float* bhh_d = (const float*)d_in[16];
    const float* Wout  = (const float*)d_in[17];
    const float* bout  = (const float*)d_in[18];
    unsigned char* ws = (unsigned char*)d_ws;
    float* out = (float*)d_out;

    const bool have_seqb = ws_size >= (size_t)WS_END;
    unsigned short* seqb = have_seqb ? (unsigned short*)(ws + WS_SEQB) : nullptr;

    hipMemsetAsync(ws, 0, WS_ZERO, stream);            // flags + hbuf0 (phase 0)
    hipMemsetAsync(ws + WS_HBUF1, 0x40, HB1_SIZE, stream);  // hbuf1: bit14=1
    if (have_seqb)
        seqcvt_kernel<<<4096, 256, 0, stream>>>(seq, seqb);
    wcomb_kernel<<<256, 256, 0, stream>>>(Wih_d, Whh_d, Wout, bih_d, bhh_d, bout, ws);
    vae_persistent<<<128, 512, 0, stream>>>(
        seq, seqb, eps, Wih_e, Whh_e, bih_e, bhh_e,
        Wmean, bmean, Wlv, blv, Winit, binit,
        Whh_d, bih_d, bhh_d, Wout, bout, ws, out);
}

// Round 10
// 2968.051 us; speedup vs baseline: 1.1142x; 1.1142x over previous
//
#include <hip/hip_runtime.h>
#include <stdint.h>

// ---------------------------------------------------------------------------
// LSTM-VAE persistent kernel, MI355X (gfx950).  B=128, T=512, I=L=64, H=512,
// 100 decoder steps.  fp32 in/out; bf16 MFMA internal.
//
// 128 WGs = 8 batch-groups(g) x 16 hidden-slices(s), block=512 (8 waves).
// Slice owns 32 hidden dims = 128 interleaved gate rows [i0,f0,g0,o0,...];
// W_hh slice in 64 VGPRs/lane as MFMA B-fragments. Decoder folds x_hat via
// W_comb = W_hh_dec + W_ih_dec@W_out; x_hat tiles on wave 7 of slices 0-3.
//
// Round-18: r17 RESUBMITTED VERBATIM.  r17 returned "container failed
// twice" with no counters.  Full re-audit (protocol, addressing,
// alignment, MFMA layout, asm constraints) found no defect; the harness
// has a documented history of flakes (Trio exception r12, 221s pushes,
// DVFS 20x outlier dispatches, r13 "failed twice" on a clean-auditing
// kernel).  Per methodology: identical re-run to discriminate infra vs
// kernel.  Second failure => condemn kernel, revert to green r14 line.
//
// r17 design (from r16 post-mortem): r16's per-wave publish caused 4x
// WRITE_SIZE (8 waves x 8B scattered into each 64B row-slice -> no write
// combining) -> 3290us.  Fix: BLOCK-LAYOUT h-buffer so the per-wave
// publish is contiguous.  Layout: per group, h = [128 blocks][16 rows]
// [8B], where block = s*8+wv holds dims s*32+wv*4+{0..3}.  A wave's
// publish is ONE 128B contiguous region (16 active lanes x dwordx2,
// single instruction, 2 full 64B lines) -> no amplification, no Ho tile,
// no funnel, no pre-publish barrier.  Consumer chunk (32B) comes from a
// single producer wave.  LDS stage = linear copy of the same layout;
// MFMA A-fragments = 2x 8B LDS reads (dims q*8+{0..3}/{4..7} in adjacent
// blocks).  ONE barrier/step.
//
// Sync: POLL-ON-DATA phase-bit protocol (r9/r10/r14/r16, HW-verified).
// |h|<=1 so bit14 of every bf16 is 0.  Round R writes buf[R&1] with each
// bf16 XOR'd by (phase(R) ? 0x4000 : 0); phase alternates on every reuse
// of a buffer.  Consumers poll their own 32B chunk until EVERY bf16
// carries the round's phase (stores dword-atomic; torn arrival keeps
// polling; stale phase is the complement).  One-shot + capped s_sleep
// backoff.  Overwrite safety: depth-2 transitive certification -- a wave
// publishes R+1 only after its WG's stage-barrier of R, certifying all
// slices published R, hence all WGs consumed R-1, hence hbuf[(R+1)&1]
// (holding R-1) is dead.  Round 513 (h_dec0) computed locally -> decoder
// rounds >=514 use the shifted phase formula.  hbuf1 pre-filled 0x40 so
// round 1 cannot false-trigger.  Flags only for the one-shot z exchange.
// All coherent ops are the proven `sc0 sc1` (LLC) path.  Monolithic
// load+waitcnt with "=&v" early-clobber (r15 crash lesson: never split
// issue/wait across asm statements).
// ---------------------------------------------------------------------------

typedef short short8 __attribute__((ext_vector_type(8)));
typedef float f32x4 __attribute__((ext_vector_type(4)));
typedef unsigned int u32x4 __attribute__((ext_vector_type(4)));
typedef unsigned int u32x2 __attribute__((ext_vector_type(2)));

#define WS_FLAGS  0           // 8 g x 16 s x 128 B (z exchange only)
#define WS_HBUF0  16384       // 128 KB
#define WS_HBUF1  147456      // 128 KB
#define WS_Z      278528      // 32 KB fp32
#define WS_BCOMB  311296      // 8 KB fp32
#define WS_WCOMB  319488      // 2 MB bf16
#define WS_SEQB   2416640     // 8 MB bf16 seq
#define WS_END    10805248
#define WS_ZERO   WS_HBUF1    // memset flags + hbuf0 (h0 = 0, phase 0)
#define HB1_SIZE  131072      // hbuf1: fill 0x40 (bit14=1, != phase 0)

#define AL_HALF   8192        // shorts per LDS tile buffer (128 blk x 16 x 4)

static __device__ __forceinline__ float b2f(unsigned short u) {
    return __builtin_bit_cast(float, (unsigned int)u << 16);
}
static __device__ __forceinline__ unsigned short f2b(float f) {
    unsigned int u = __builtin_bit_cast(unsigned int, f);
    unsigned int r = u + 0x7FFFu + ((u >> 16) & 1u);  // RNE
    return (unsigned short)(r >> 16);
}
static __device__ __forceinline__ float sigm(float x)  { return 1.0f / (1.0f + __expf(-x)); }
static __device__ __forceinline__ float tanhx(float x) { return 1.0f - 2.0f / (__expf(2.0f * x) + 1.0f); }

static __device__ __forceinline__ short8 cvt8(const float* p) {
    const float4 a = ((const float4*)p)[0];
    const float4 b = ((const float4*)p)[1];
    short8 r;
    r[0] = (short)f2b(a.x); r[1] = (short)f2b(a.y);
    r[2] = (short)f2b(a.z); r[3] = (short)f2b(a.w);
    r[4] = (short)f2b(b.x); r[5] = (short)f2b(b.y);
    r[6] = (short)f2b(b.z); r[7] = (short)f2b(b.w);
    return r;
}

// phase(R): encoder/VAE rounds 0..512: (R>>1)&1.  Round 513 skipped (local
// h_dec0).  Decoder rounds 514..613 shifted so every buffer reuse still
// alternates (buf0: 512(0),514(1),516(0)..; buf1: 511(1),515(0),517(1)..).
static __device__ __forceinline__ uint32_t phase_of(uint32_t R) {
    return (R <= 512u) ? ((R >> 1) & 1u)
                       : ((((R - 513u) >> 1) & 1u) ^ 1u);
}

// --- coherent (LLC-served) coalesced ops: sc0 sc1 -------------------------
static __device__ __forceinline__ void load2x16_cc(const void* p0, const void* p1,
                                                   u32x4& v0, u32x4& v1) {
    asm volatile("global_load_dwordx4 %0, %2, off sc0 sc1\n\t"
                 "global_load_dwordx4 %1, %3, off sc0 sc1\n\t"
                 "s_waitcnt vmcnt(0)"
                 : "=&v"(v0), "=&v"(v1) : "v"(p0), "v"(p1) : "memory");
}
static __device__ __forceinline__ void drain_vm() {
    asm volatile("s_waitcnt vmcnt(0)" ::: "memory");
}

// ---------------------------------------------------------------------------
// Prologue A: seq fp32 -> bf16
// ---------------------------------------------------------------------------
__global__ void __launch_bounds__(256)
seqcvt_kernel(const float* __restrict__ src, unsigned short* __restrict__ dst)
{
    int i = (blockIdx.x * 256 + threadIdx.x) * 4;
    float4 v = *(const float4*)(src + i);
    uint32_t lo = (uint32_t)f2b(v.x) | ((uint32_t)f2b(v.y) << 16);
    uint32_t hi = (uint32_t)f2b(v.z) | ((uint32_t)f2b(v.w) << 16);
    uint2 o; o.x = lo; o.y = hi;
    *(uint2*)(dst + i) = o;
}

// ---------------------------------------------------------------------------
// Prologue B: W_comb = W_hh_dec + W_ih_dec @ W_out (bf16 out), b_comb (fp32)
// ---------------------------------------------------------------------------
__global__ void __launch_bounds__(256)
wcomb_kernel(const float* __restrict__ Wih_d,
             const float* __restrict__ Whh_d,
             const float* __restrict__ Wout,
             const float* __restrict__ bih_d,
             const float* __restrict__ bhh_d,
             const float* __restrict__ bout,
             unsigned char* __restrict__ ws)
{
    __shared__ float Ash[64][64];
    __shared__ float Bsh[64][65];
    const int bid = blockIdx.x, t = threadIdx.x;
    const int gt0 = (bid >> 3) * 64, ht0 = (bid & 7) * 64;
    for (int j = 0; j < 16; ++j) {
        int idx = t + j * 256;
        int r = idx >> 6, c = idx & 63;
        Ash[r][c] = Wih_d[(size_t)(gt0 + r) * 64 + c];
        Bsh[r][c] = Wout[(size_t)r * 512 + ht0 + c];
    }
    __syncthreads();
    const int gl = t >> 2, hl0 = (t & 3) * 16;
    for (int hh = 0; hh < 16; ++hh) {
        float acc = 0.f;
        #pragma unroll
        for (int i = 0; i < 64; ++i) acc += Ash[gl][i] * Bsh[i][hl0 + hh];
        int g = gt0 + gl, h = ht0 + hl0 + hh;
        float v = Whh_d[(size_t)g * 512 + h] + acc;
        ((unsigned short*)(ws + WS_WCOMB))[(size_t)g * 512 + h] = f2b(v);
    }
    if ((bid & 7) == 0 && t < 64) {
        int g = gt0 + t;
        float acc = bih_d[g] + bhh_d[g];
        #pragma unroll
        for (int i = 0; i < 64; ++i) acc += bout[i] * Ash[t][i];
        ((float*)(ws + WS_BCOMB))[g] = acc;
    }
}

// ---------------------------------------------------------------------------
// Main persistent kernel
// ---------------------------------------------------------------------------
__global__ void __launch_bounds__(512, 2)
vae_persistent(const float* __restrict__ seq,
               const unsigned short* __restrict__ seqb,
               const float* __restrict__ eps,
               const float* __restrict__ Wih_e,
               const float* __restrict__ Whh_e,
               const float* __restrict__ bih_e,
               const float* __restrict__ bhh_e,
               const float* __restrict__ Wmean,
               const float* __restrict__ bmean,
               const float* __restrict__ Wlv,
               const float* __restrict__ blv,
               const float* __restrict__ Winit,
               const float* __restrict__ binit,
               const float* __restrict__ Whh_d,
               const float* __restrict__ bih_d,
               const float* __restrict__ bhh_d,
               const float* __restrict__ Wout,
               const float* __restrict__ bout,
               unsigned char* __restrict__ ws,
               float* __restrict__ out)
{
    __shared__ __align__(16) short Al[2 * AL_HALF];  // double-buffered h tile
    __shared__ float fbuf[128];                      // mean/logvar scratch
    __shared__ float zl[16 * 64];                    // z tile (fp32)

    const int tid  = threadIdx.x;
    const int g    = blockIdx.x & 7;        // batch group
    const int s    = blockIdx.x >> 3;       // hidden slice
    const int b0   = g * 16;
    const int lane = tid & 63;
    const int wv   = tid >> 6;
    const int col  = lane & 15;
    const int q    = lane >> 4;
    const int nloc = wv * 16 + col;
    const int gt   = nloc & 3;              // 0=i,1=f,2=g,3=o
    const int grow = gt * 512 + s * 32 + (nloc >> 2);

    uint32_t* flags = (uint32_t*)(ws + WS_FLAGS) + (size_t)g * 512;  // z only
    unsigned char* hbuf0 = ws + WS_HBUF0;
    unsigned char* hbuf1 = ws + WS_HBUF1;
    uint32_t* zbuf = (uint32_t*)(ws + WS_Z);

    float cst[4] = {0.f, 0.f, 0.f, 0.f};

    // Fragment LDS offsets (shorts): frag kt = dims kt*32+q*8+{0..7}, batch
    // col -> blocks kt*8+q*2 (+1), row col.  off + {0..3} then off+64+{0..3}.
    int aoff[16];
    #pragma unroll
    for (int kt = 0; kt < 16; ++kt)
        aoff[kt] = (kt * 8 + q * 2) * 64 + col * 4;
    // staging chunk: thread covers block bl = tid>>2, rows (tid&3)*4..+4
    const int stg_byte = (tid >> 2) * 128 + (tid & 3) * 32;   // in 16KB tile
    const int stg_di   = (tid >> 2) * 8 + (tid & 3) * 2;      // u32x4 index

    auto ldfrag = [&](const short* ab, int kt) -> short8 {
        uint2 lo = *(const uint2*)(ab + aoff[kt]);
        uint2 hi = *(const uint2*)(ab + aoff[kt] + 64);
        u32x4 w; w[0] = lo.x; w[1] = lo.y; w[2] = hi.x; w[3] = hi.y;
        return __builtin_bit_cast(short8, w);
    };

    // ---- stage round R into Al[R&1]: monolithic one-shot + backoff poll --
    auto wait_and_stage = [&](uint32_t R) {
        const unsigned char* src = ((R & 1) ? hbuf1 : hbuf0) + (size_t)g * 16384;
        const uint32_t pm = phase_of(R) ? 0x40004000u : 0u;
        const unsigned char* p0 = src + stg_byte;
        u32x4 v0, v1;
        uint32_t tries = 0;
        for (;;) {
            load2x16_cc(p0, p0 + 16, v0, v1);
            uint32_t bad = 0;
            #pragma unroll
            for (int i = 0; i < 4; ++i) {
                bad |= (v0[i] & 0x40004000u) ^ pm;
                bad |= (v1[i] & 0x40004000u) ^ pm;
            }
            if (bad == 0) break;               // per-lane exit
            if (tries == 1)      __builtin_amdgcn_s_sleep(1);
            else if (tries == 2) __builtin_amdgcn_s_sleep(2);
            else if (tries >= 3) __builtin_amdgcn_s_sleep(4);  // capped (DVFS)
            ++tries;
        }
        #pragma unroll
        for (int i = 0; i < 4; ++i) { v0[i] ^= pm; v1[i] ^= pm; }
        u32x4* dst = (u32x4*)(Al + (R & 1) * AL_HALF);   // linear copy
        dst[stg_di]     = v0;
        dst[stg_di + 1] = v1;
        __syncthreads();                       // the ONE barrier per step
    };

    // ---- cell update + per-wave COALESCED publish of round R -------------
    // Wave wv owns block s*8+wv (dims s*32+wv*4+{0..3}, 16 rows x 8B =
    // 128B contiguous).  Lane l = q*16+r (col==r) stores row q*4+r's 8B:
    // 16 active lanes, ascending addresses -> full-line combining.
    auto cell_publish = [&](f32x4 acc, uint32_t R) {
        float act[4];
        #pragma unroll
        for (int r = 0; r < 4; ++r)
            act[r] = (gt == 2) ? tanhx(acc[r]) : sigm(acc[r]);
        int base = lane & ~3;
        #pragma unroll
        for (int r = 0; r < 4; ++r) {
            float vi = __shfl(act[r], base + 0);
            float vf = __shfl(act[r], base + 1);
            float vg = __shfl(act[r], base + 2);
            float vo = __shfl(act[r], base + 3);
            cst[r] = vf * cst[r] + vi * vg;
            act[r] = vo * tanhx(cst[r]);
        }
        unsigned char* dst = ((R & 1) ? hbuf1 : hbuf0) + (size_t)g * 16384
                             + (s * 8 + wv) * 128;
        const uint32_t pm = phase_of(R) ? 0x40004000u : 0u;
        const int qb = lane & 48;
        #pragma unroll
        for (int r = 0; r < 4; ++r) {
            uint32_t u = (uint32_t)f2b(act[r]);
            uint32_t g0 = (uint32_t)__shfl((int)u, qb + 0);
            uint32_t g1 = (uint32_t)__shfl((int)u, qb + 4);
            uint32_t g2 = (uint32_t)__shfl((int)u, qb + 8);
            uint32_t g3 = (uint32_t)__shfl((int)u, qb + 12);
            if (col == r) {
                u32x2 pk;
                pk[0] = (g0 | (g1 << 16)) ^ pm;
                pk[1] = (g2 | (g3 << 16)) ^ pm;
                void* p = dst + (q * 4 + r) * 8;
                asm volatile("global_store_dwordx2 %0, %1, off sc0 sc1"
                             :: "v"(p), "v"(pk) : "memory");
            }
        }
    };

    short8 wfrag[16];
    auto load_wfrag_f32 = [&](const float* Wsrc) {
        #pragma unroll
        for (int kt = 0; kt < 16; ++kt)
            wfrag[kt] = cvt8(Wsrc + (size_t)grow * 512 + kt * 32 + q * 8);
    };
    auto load_wfrag_bf16 = [&](const unsigned short* Wsrc) {
        #pragma unroll
        for (int kt = 0; kt < 16; ++kt)
            wfrag[kt] = *(const short8*)((const short*)Wsrc +
                         (size_t)grow * 512 + kt * 32 + q * 8);
    };

    // ---------------- encoder: 512 steps ----------------
    load_wfrag_f32(Whh_e);
    short8 xwf[2];
    #pragma unroll
    for (int kt = 0; kt < 2; ++kt)
        xwf[kt] = cvt8(Wih_e + (size_t)grow * 64 + kt * 32 + q * 8);
    const float bias_e = bih_e[grow] + bhh_e[grow];

    auto load_x = [&](int t, short8* xf) {
        if (seqb) {
            const short* xs = (const short*)seqb + ((size_t)(b0 + col) * 512 + t) * 64 + q * 8;
            xf[0] = *(const short8*)(xs);
            xf[1] = *(const short8*)(xs + 32);
        } else {
            const float* xs = seq + ((size_t)(b0 + col) * 512 + t) * 64 + q * 8;
            xf[0] = cvt8(xs);
            xf[1] = cvt8(xs + 32);
        }
    };

    short8 xf[2];
    load_x(0, xf);
    for (uint32_t t = 0; t < 512; ++t) {
        // x-part first: independent of Al, overlaps the poll
        f32x4 acc = {bias_e, bias_e, bias_e, bias_e};
        acc = __builtin_amdgcn_mfma_f32_16x16x32_bf16(xf[0], xwf[0], acc, 0, 0, 0);
        acc = __builtin_amdgcn_mfma_f32_16x16x32_bf16(xf[1], xwf[1], acc, 0, 0, 0);
        if (t < 511) load_x(t + 1, xf);
        wait_and_stage(t);                   // t=0: hbuf0 zeros, phase 0 -> instant
        const short* ab = Al + (t & 1) * AL_HALF;
        f32x4 acc1 = {0.f, 0.f, 0.f, 0.f};   // 2 chains: halve serial latency
        #pragma unroll
        for (int kt = 0; kt < 16; kt += 2) {
            short8 a0 = ldfrag(ab, kt);
            short8 a1 = ldfrag(ab, kt + 1);
            acc  = __builtin_amdgcn_mfma_f32_16x16x32_bf16(a0, wfrag[kt],     acc,  0, 0, 0);
            acc1 = __builtin_amdgcn_mfma_f32_16x16x32_bf16(a1, wfrag[kt + 1], acc1, 0, 0, 0);
        }
        #pragma unroll
        for (int r = 0; r < 4; ++r) acc[r] += acc1[r];
        cell_publish(acc, t + 1);            // per-wave coalesced, no barrier
    }

    // ---------------- VAE reparameterization (flag 513 = z ready) ---------
    wait_and_stage(512);                     // Al[0] = h_n (block layout)
    if (tid < 128) {
        int which = tid >> 6, idx = tid & 63;
        int b = idx >> 2, ldl = idx & 3;
        int ld = s * 4 + ldl;
        const float* wrow = (which ? Wlv : Wmean) + (size_t)ld * 512;
        float a = (which ? blv[ld] : bmean[ld]);
        for (int u = 0; u < 128; ++u) {      // block u = dims u*4+{0..3}
            const short* ap = Al + u * 64 + b * 4;
            const float* wp = wrow + u * 4;
            #pragma unroll
            for (int e = 0; e < 4; ++e)
                a += b2f((unsigned short)ap[e]) * wp[e];
        }
        out[819200 + which * 8192 + (size_t)(b0 + b) * 64 + ld] = a;
        fbuf[which * 64 + idx] = a;
    }
    __syncthreads();
    if (wv == 0) {
        int b = lane >> 2, ldl = lane & 3;
        int ld = s * 4 + ldl;
        float m = fbuf[lane], lv = fbuf[64 + lane];
        float e = eps[(size_t)(b0 + b) * 64 + ld];
        float z = m + e * __expf(0.5f * lv);
        __hip_atomic_store(zbuf + (size_t)(b0 + b) * 64 + ld,
                           __builtin_bit_cast(uint32_t, z),
                           __ATOMIC_RELAXED, __HIP_MEMORY_SCOPE_AGENT);
        drain_vm();
        if (lane == 0)
            __hip_atomic_store(&flags[s * 32], 513u,
                               __ATOMIC_RELAXED, __HIP_MEMORY_SCOPE_AGENT);
    }
    if (wv == 0 && lane < 16)
        while (__hip_atomic_load(&flags[lane * 32], __ATOMIC_RELAXED,
                                 __HIP_MEMORY_SCOPE_AGENT) < 513u) {}
    __syncthreads();

    // h_dec0 = z @ W_init^T + b_init -> Al[1] (round-513 parity, block layout)
    #pragma unroll
    for (int j = 0; j < 2; ++j) {
        int idx = tid + j * 512;
        int b = idx >> 6, l = idx & 63;
        uint32_t v = __hip_atomic_load(zbuf + (size_t)(b0 + b) * 64 + l,
                                       __ATOMIC_RELAXED, __HIP_MEMORY_SCOPE_AGENT);
        zl[b * 64 + l] = __builtin_bit_cast(float, v);
    }
    __syncthreads();
    {
        int b = tid >> 5, c = tid & 31;
        #pragma unroll
        for (int j = 0; j < 16; ++j) {
            int hd = c * 16 + j;
            float a = binit[hd];
            const float* wr = Winit + (size_t)hd * 64;
            #pragma unroll
            for (int l = 0; l < 64; ++l) a += zl[b * 64 + l] * wr[l];
            Al[AL_HALF + (hd >> 2) * 64 + b * 4 + (hd & 3)] = (short)f2b(a);
        }
    }
    #pragma unroll
    for (int r = 0; r < 4; ++r) cst[r] = 0.f;
    __syncthreads();

    // -------- decoder: 100 steps; step d publishes h_{d+1} as R=514+d -----
    short8 wof[16];
    float xbias = 0.f;
    if (s < 4 && wv == 7) {                  // x_hat tile s on wave 7 (no duties)
        xbias = bout[s * 16 + col];
        #pragma unroll
        for (int kt = 0; kt < 16; ++kt)
            wof[kt] = cvt8(Wout + (size_t)(s * 16 + col) * 512 + kt * 32 + q * 8);
    }
    auto xhat_emit = [&](int d, const short* ab) {  // x_hat_d from ab (= h_{d+1})
        f32x4 a2 = {xbias, xbias, xbias, xbias};
        #pragma unroll
        for (int kt = 0; kt < 16; ++kt) {
            short8 a = ldfrag(ab, kt);
            a2 = __builtin_amdgcn_mfma_f32_16x16x32_bf16(a, wof[kt], a2, 0, 0, 0);
        }
        #pragma unroll
        for (int r = 0; r < 4; ++r) {
            int b = q * 4 + r;
            out[((size_t)(b0 + b) * 100 + d) * 64 + s * 16 + col] = a2[r];
        }
    };

    load_wfrag_f32(Whh_d);                   // step 0: x0 == 0
    float bias = bih_d[grow] + bhh_d[grow];
    for (uint32_t d = 0; d < 100; ++d) {
        const uint32_t Rin = 513 + d;        // round holding h_d
        if (d > 0) wait_and_stage(Rin);      // Al[Rin&1] = h_d
        const short* ab = Al + (Rin & 1) * AL_HALF;
        f32x4 acc = {bias, bias, bias, bias};
        f32x4 acc1 = {0.f, 0.f, 0.f, 0.f};
        #pragma unroll
        for (int kt = 0; kt < 16; kt += 2) {
            short8 a0 = ldfrag(ab, kt);
            short8 a1 = ldfrag(ab, kt + 1);
            acc  = __builtin_amdgcn_mfma_f32_16x16x32_bf16(a0, wfrag[kt],     acc,  0, 0, 0);
            acc1 = __builtin_amdgcn_mfma_f32_16x16x32_bf16(a1, wfrag[kt + 1], acc1, 0, 0, 0);
        }
        #pragma unroll
        for (int r = 0; r < 4; ++r) acc[r] += acc1[r];
        cell_publish(acc, 514 + d);
        if (d >= 1 && s < 4 && wv == 7) xhat_emit(d - 1, ab);  // opposite parity
        if (d == 0) {                                          // vs next staging
            load_wfrag_bf16((const unsigned short*)(ws + WS_WCOMB));
            bias = ((const float*)(ws + WS_BCOMB))[grow];
        }
    }
    wait_and_stage(613);                     // Al[1] = h_100
    if (s < 4 && wv == 7) xhat_emit(99, Al + AL_HALF);
}

extern "C" void kernel_launch(void* const* d_in, const int* in_sizes, int n_in,
                              void* d_out, int out_size, void* d_ws, size_t ws_size,
                              hipStream_t stream) {
    (void)in_sizes; (void)n_in; (void)out_size;
    const float* seq   = (const float*)d_in[0];
    const float* eps   = (const float*)d_in[2];
    const float* Wih_e = (const float*)d_in[3];
    const float* Whh_e = (const float*)d_in[4];
    const float* bih_e = (const float*)d_in[5];
    const float* bhh_e = (const float*)d_in[6];
    const float* Wmean = (const float*)d_in[7];
    const float* bmean = (const float*)d_in[8];
    const float* Wlv   = (const float*)d_in[9];
    const float* blv   = (const float*)d_in[10];
    const float* Winit = (const float*)d_in[11];
    const float* binit = (const float*)d_in[12];
    const float* Wih_d = (const float*)d_in[13];
    const float* Whh_d = (const float*)d_in[14];
    const float* bih_d = (const float*)d_in[15];
    const float* bhh_d = (const float*)d_in[16];
    const float* Wout  = (const float*)d_in[17];
    const float* bout  = (const float*)d_in[18];
    unsigned char* ws = (unsigned char*)d_ws;
    float* out = (float*)d_out;

    const bool have_seqb = ws_size >= (size_t)WS_END;
    unsigned short* seqb = have_seqb ? (unsigned short*)(ws + WS_SEQB) : nullptr;

    hipMemsetAsync(ws, 0, WS_ZERO, stream);            // flags + hbuf0 (phase 0)
    hipMemsetAsync(ws + WS_HBUF1, 0x40, HB1_SIZE, stream);  // hbuf1: bit14=1
    if (have_seqb)
        seqcvt_kernel<<<4096, 256, 0, stream>>>(seq, seqb);
    wcomb_kernel<<<256, 256, 0, stream>>>(Wih_d, Whh_d, Wout, bih_d, bhh_d, bout, ws);
    vae_persistent<<<128, 512, 0, stream>>>(
        seq, seqb, eps, Wih_e, Whh_e, bih_e, bhh_e,
        Wmean, bmean, Wlv, blv, Winit, binit,
        Whh_d, bih_d, bhh_d, Wout, bout, ws, out);
}

// Round 11
// 2378.413 us; speedup vs baseline: 1.3904x; 1.2479x over previous
//
#include <hip/hip_runtime.h>
#include <stdint.h>

// ---------------------------------------------------------------------------
// LSTM-VAE persistent kernel, MI355X (gfx950).  B=128, T=512, I=L=64, H=512,
// 100 decoder steps.  fp32 in/out; bf16 MFMA internal.
//
// 128 WGs = 8 batch-groups(g) x 16 hidden-slices(s), block=512 (8 waves).
// Slice owns 32 hidden dims = 128 interleaved gate rows [i0,f0,g0,o0,...];
// W_hh slice in 64 VGPRs/lane as MFMA B-fragments. Decoder folds x_hat via
// W_comb = W_hh_dec + W_ih_dec@W_out; x_hat tiles on wave 7 of slices 0-3.
//
// Round-19 (r18 post-mortem): r18's publish was NOT coalesced -- the store
// sat inside the r-loop under `col==r`, so each instruction had only 4
// active lanes x 8B at stride 32 (partial lines -> RMW write-through ->
// WRITE_SIZE stayed 318MB, dur 2871us).  The sc0sc1 exchange writes
// through to HBM (r14/r18 FETCH arithmetic: first reader of each line
// pays an HBM miss, later readers hit LLC), so write amplification
// multiplies first-touch latency on the critical path.
//   FIX (single change): compute all four packed row-values in EVERY lane
//   (shfls already run in all lanes), select by col via a static ternary
//   chain (cndmasks, no dynamic reg indexing), and issue ONE store with
//   16 active lanes covering the wave's 128B block contiguously (offsets
//   0..120) -> two full 64B lines, no RMW.
// Block layout (r17, validated by bank-conflict 4.1e7 -> 1.09e7): per
// group, h = [128 blocks][16 rows][8B], block = s*8+wv holds dims
// s*32+wv*4+{0..3}.  LDS stage = linear copy; MFMA A-fragments = 2x 8B
// LDS reads.  ONE barrier/step, no Ho tile, no wave-0 funnel.
//
// Sync: POLL-ON-DATA phase-bit protocol (r9/r10/r14/r16/r18, HW-verified).
// |h|<=1 so bit14 of every bf16 is 0.  Round R writes buf[R&1] with each
// bf16 XOR'd by (phase(R) ? 0x4000 : 0); phase alternates on every reuse
// of a buffer.  Consumers poll their own 32B chunk until EVERY bf16
// carries the round's phase (stores dword-atomic; torn arrival keeps
// polling; stale phase is the complement).  One-shot + capped s_sleep
// backoff.  Overwrite safety: depth-2 transitive certification -- a wave
// publishes R+1 only after its WG's stage-barrier of R, certifying all
// slices published R, hence all WGs consumed R-1, hence hbuf[(R+1)&1]
// (holding R-1) is dead.  Round 513 (h_dec0) computed locally -> decoder
// rounds >=514 use the shifted phase formula.  hbuf1 pre-filled 0x40 so
// round 1 cannot false-trigger.  Flags only for the one-shot z exchange.
// All coherent ops are the proven `sc0 sc1` (LLC) path.  Monolithic
// load+waitcnt with "=&v" early-clobber (r15 crash lesson: never split
// issue/wait across asm statements).
// ---------------------------------------------------------------------------

typedef short short8 __attribute__((ext_vector_type(8)));
typedef float f32x4 __attribute__((ext_vector_type(4)));
typedef unsigned int u32x4 __attribute__((ext_vector_type(4)));
typedef unsigned int u32x2 __attribute__((ext_vector_type(2)));

#define WS_FLAGS  0           // 8 g x 16 s x 128 B (z exchange only)
#define WS_HBUF0  16384       // 128 KB
#define WS_HBUF1  147456      // 128 KB
#define WS_Z      278528      // 32 KB fp32
#define WS_BCOMB  311296      // 8 KB fp32
#define WS_WCOMB  319488      // 2 MB bf16
#define WS_SEQB   2416640     // 8 MB bf16 seq
#define WS_END    10805248
#define WS_ZERO   WS_HBUF1    // memset flags + hbuf0 (h0 = 0, phase 0)
#define HB1_SIZE  131072      // hbuf1: fill 0x40 (bit14=1, != phase 0)

#define AL_HALF   8192        // shorts per LDS tile buffer (128 blk x 16 x 4)

static __device__ __forceinline__ float b2f(unsigned short u) {
    return __builtin_bit_cast(float, (unsigned int)u << 16);
}
static __device__ __forceinline__ unsigned short f2b(float f) {
    unsigned int u = __builtin_bit_cast(unsigned int, f);
    unsigned int r = u + 0x7FFFu + ((u >> 16) & 1u);  // RNE
    return (unsigned short)(r >> 16);
}
static __device__ __forceinline__ float sigm(float x)  { return 1.0f / (1.0f + __expf(-x)); }
static __device__ __forceinline__ float tanhx(float x) { return 1.0f - 2.0f / (__expf(2.0f * x) + 1.0f); }

static __device__ __forceinline__ short8 cvt8(const float* p) {
    const float4 a = ((const float4*)p)[0];
    const float4 b = ((const float4*)p)[1];
    short8 r;
    r[0] = (short)f2b(a.x); r[1] = (short)f2b(a.y);
    r[2] = (short)f2b(a.z); r[3] = (short)f2b(a.w);
    r[4] = (short)f2b(b.x); r[5] = (short)f2b(b.y);
    r[6] = (short)f2b(b.z); r[7] = (short)f2b(b.w);
    return r;
}

// phase(R): encoder/VAE rounds 0..512: (R>>1)&1.  Round 513 skipped (local
// h_dec0).  Decoder rounds 514..613 shifted so every buffer reuse still
// alternates (buf0: 512(0),514(1),516(0)..; buf1: 511(1),515(0),517(1)..).
static __device__ __forceinline__ uint32_t phase_of(uint32_t R) {
    return (R <= 512u) ? ((R >> 1) & 1u)
                       : ((((R - 513u) >> 1) & 1u) ^ 1u);
}

// --- coherent (LLC-served) coalesced ops: sc0 sc1 -------------------------
static __device__ __forceinline__ void load2x16_cc(const void* p0, const void* p1,
                                                   u32x4& v0, u32x4& v1) {
    asm volatile("global_load_dwordx4 %0, %2, off sc0 sc1\n\t"
                 "global_load_dwordx4 %1, %3, off sc0 sc1\n\t"
                 "s_waitcnt vmcnt(0)"
                 : "=&v"(v0), "=&v"(v1) : "v"(p0), "v"(p1) : "memory");
}
static __device__ __forceinline__ void drain_vm() {
    asm volatile("s_waitcnt vmcnt(0)" ::: "memory");
}

// ---------------------------------------------------------------------------
// Prologue A: seq fp32 -> bf16
// ---------------------------------------------------------------------------
__global__ void __launch_bounds__(256)
seqcvt_kernel(const float* __restrict__ src, unsigned short* __restrict__ dst)
{
    int i = (blockIdx.x * 256 + threadIdx.x) * 4;
    float4 v = *(const float4*)(src + i);
    uint32_t lo = (uint32_t)f2b(v.x) | ((uint32_t)f2b(v.y) << 16);
    uint32_t hi = (uint32_t)f2b(v.z) | ((uint32_t)f2b(v.w) << 16);
    uint2 o; o.x = lo; o.y = hi;
    *(uint2*)(dst + i) = o;
}

// ---------------------------------------------------------------------------
// Prologue B: W_comb = W_hh_dec + W_ih_dec @ W_out (bf16 out), b_comb (fp32)
// ---------------------------------------------------------------------------
__global__ void __launch_bounds__(256)
wcomb_kernel(const float* __restrict__ Wih_d,
             const float* __restrict__ Whh_d,
             const float* __restrict__ Wout,
             const float* __restrict__ bih_d,
             const float* __restrict__ bhh_d,
             const float* __restrict__ bout,
             unsigned char* __restrict__ ws)
{
    __shared__ float Ash[64][64];
    __shared__ float Bsh[64][65];
    const int bid = blockIdx.x, t = threadIdx.x;
    const int gt0 = (bid >> 3) * 64, ht0 = (bid & 7) * 64;
    for (int j = 0; j < 16; ++j) {
        int idx = t + j * 256;
        int r = idx >> 6, c = idx & 63;
        Ash[r][c] = Wih_d[(size_t)(gt0 + r) * 64 + c];
        Bsh[r][c] = Wout[(size_t)r * 512 + ht0 + c];
    }
    __syncthreads();
    const int gl = t >> 2, hl0 = (t & 3) * 16;
    for (int hh = 0; hh < 16; ++hh) {
        float acc = 0.f;
        #pragma unroll
        for (int i = 0; i < 64; ++i) acc += Ash[gl][i] * Bsh[i][hl0 + hh];
        int g = gt0 + gl, h = ht0 + hl0 + hh;
        float v = Whh_d[(size_t)g * 512 + h] + acc;
        ((unsigned short*)(ws + WS_WCOMB))[(size_t)g * 512 + h] = f2b(v);
    }
    if ((bid & 7) == 0 && t < 64) {
        int g = gt0 + t;
        float acc = bih_d[g] + bhh_d[g];
        #pragma unroll
        for (int i = 0; i < 64; ++i) acc += bout[i] * Ash[t][i];
        ((float*)(ws + WS_BCOMB))[g] = acc;
    }
}

// ---------------------------------------------------------------------------
// Main persistent kernel
// ---------------------------------------------------------------------------
__global__ void __launch_bounds__(512, 2)
vae_persistent(const float* __restrict__ seq,
               const unsigned short* __restrict__ seqb,
               const float* __restrict__ eps,
               const float* __restrict__ Wih_e,
               const float* __restrict__ Whh_e,
               const float* __restrict__ bih_e,
               const float* __restrict__ bhh_e,
               const float* __restrict__ Wmean,
               const float* __restrict__ bmean,
               const float* __restrict__ Wlv,
               const float* __restrict__ blv,
               const float* __restrict__ Winit,
               const float* __restrict__ binit,
               const float* __restrict__ Whh_d,
               const float* __restrict__ bih_d,
               const float* __restrict__ bhh_d,
               const float* __restrict__ Wout,
               const float* __restrict__ bout,
               unsigned char* __restrict__ ws,
               float* __restrict__ out)
{
    __shared__ __align__(16) short Al[2 * AL_HALF];  // double-buffered h tile
    __shared__ float fbuf[128];                      // mean/logvar scratch
    __shared__ float zl[16 * 64];                    // z tile (fp32)

    const int tid  = threadIdx.x;
    const int g    = blockIdx.x & 7;        // batch group
    const int s    = blockIdx.x >> 3;       // hidden slice
    const int b0   = g * 16;
    const int lane = tid & 63;
    const int wv   = tid >> 6;
    const int col  = lane & 15;
    const int q    = lane >> 4;
    const int nloc = wv * 16 + col;
    const int gt   = nloc & 3;              // 0=i,1=f,2=g,3=o
    const int grow = gt * 512 + s * 32 + (nloc >> 2);

    uint32_t* flags = (uint32_t*)(ws + WS_FLAGS) + (size_t)g * 512;  // z only
    unsigned char* hbuf0 = ws + WS_HBUF0;
    unsigned char* hbuf1 = ws + WS_HBUF1;
    uint32_t* zbuf = (uint32_t*)(ws + WS_Z);

    float cst[4] = {0.f, 0.f, 0.f, 0.f};

    // Fragment LDS offsets (shorts): frag kt = dims kt*32+q*8+{0..7}, batch
    // col -> blocks kt*8+q*2 (+1), row col.  off + {0..3} then off+64+{0..3}.
    int aoff[16];
    #pragma unroll
    for (int kt = 0; kt < 16; ++kt)
        aoff[kt] = (kt * 8 + q * 2) * 64 + col * 4;
    // staging chunk: thread covers block bl = tid>>2, rows (tid&3)*4..+4
    const int stg_byte = (tid >> 2) * 128 + (tid & 3) * 32;   // in 16KB tile
    const int stg_di   = (tid >> 2) * 8 + (tid & 3) * 2;      // u32x4 index

    auto ldfrag = [&](const short* ab, int kt) -> short8 {
        uint2 lo = *(const uint2*)(ab + aoff[kt]);
        uint2 hi = *(const uint2*)(ab + aoff[kt] + 64);
        u32x4 w; w[0] = lo.x; w[1] = lo.y; w[2] = hi.x; w[3] = hi.y;
        return __builtin_bit_cast(short8, w);
    };

    // ---- stage round R into Al[R&1]: monolithic one-shot + backoff poll --
    auto wait_and_stage = [&](uint32_t R) {
        const unsigned char* src = ((R & 1) ? hbuf1 : hbuf0) + (size_t)g * 16384;
        const uint32_t pm = phase_of(R) ? 0x40004000u : 0u;
        const unsigned char* p0 = src + stg_byte;
        u32x4 v0, v1;
        uint32_t tries = 0;
        for (;;) {
            load2x16_cc(p0, p0 + 16, v0, v1);
            uint32_t bad = 0;
            #pragma unroll
            for (int i = 0; i < 4; ++i) {
                bad |= (v0[i] & 0x40004000u) ^ pm;
                bad |= (v1[i] & 0x40004000u) ^ pm;
            }
            if (bad == 0) break;               // per-lane exit
            if (tries == 1)      __builtin_amdgcn_s_sleep(1);
            else if (tries == 2) __builtin_amdgcn_s_sleep(2);
            else if (tries >= 3) __builtin_amdgcn_s_sleep(4);  // capped (DVFS)
            ++tries;
        }
        #pragma unroll
        for (int i = 0; i < 4; ++i) { v0[i] ^= pm; v1[i] ^= pm; }
        u32x4* dst = (u32x4*)(Al + (R & 1) * AL_HALF);   // linear copy
        dst[stg_di]     = v0;
        dst[stg_di + 1] = v1;
        __syncthreads();                       // the ONE barrier per step
    };

    // ---- cell update + per-wave COALESCED publish of round R -------------
    // Wave wv owns block s*8+wv (dims s*32+wv*4+{0..3}, 16 rows x 8B =
    // 128B contiguous).  r18 bug: store under `col==r` inside the r-loop
    // -> 4 lanes x 8B stride-32 per instruction -> partial lines -> RMW.
    // r19 fix: compute all four rows' packed values in EVERY lane, select
    // by col (static ternary -> cndmask), then ONE store with 16 active
    // lanes (col<4, offsets (q*4+col)*8 = 0..120 contiguous) -> two full
    // 64B lines per wave, no amplification.
    auto cell_publish = [&](f32x4 acc, uint32_t R) {
        float act[4];
        #pragma unroll
        for (int r = 0; r < 4; ++r)
            act[r] = (gt == 2) ? tanhx(acc[r]) : sigm(acc[r]);
        int base = lane & ~3;
        #pragma unroll
        for (int r = 0; r < 4; ++r) {
            float vi = __shfl(act[r], base + 0);
            float vf = __shfl(act[r], base + 1);
            float vg = __shfl(act[r], base + 2);
            float vo = __shfl(act[r], base + 3);
            cst[r] = vf * cst[r] + vi * vg;
            act[r] = vo * tanhx(cst[r]);
        }
        unsigned char* dst = ((R & 1) ? hbuf1 : hbuf0) + (size_t)g * 16384
                             + (s * 8 + wv) * 128;
        const uint32_t pm = phase_of(R) ? 0x40004000u : 0u;
        const int qb = lane & 48;
        uint32_t pl0, ph0, pl1, ph1, pl2, ph2, pl3, ph3;
        {
            uint32_t u, g0, g1, g2, g3;
            u = (uint32_t)f2b(act[0]);
            g0 = (uint32_t)__shfl((int)u, qb + 0);  g1 = (uint32_t)__shfl((int)u, qb + 4);
            g2 = (uint32_t)__shfl((int)u, qb + 8);  g3 = (uint32_t)__shfl((int)u, qb + 12);
            pl0 = (g0 | (g1 << 16)) ^ pm;  ph0 = (g2 | (g3 << 16)) ^ pm;
            u = (uint32_t)f2b(act[1]);
            g0 = (uint32_t)__shfl((int)u, qb + 0);  g1 = (uint32_t)__shfl((int)u, qb + 4);
            g2 = (uint32_t)__shfl((int)u, qb + 8);  g3 = (uint32_t)__shfl((int)u, qb + 12);
            pl1 = (g0 | (g1 << 16)) ^ pm;  ph1 = (g2 | (g3 << 16)) ^ pm;
            u = (uint32_t)f2b(act[2]);
            g0 = (uint32_t)__shfl((int)u, qb + 0);  g1 = (uint32_t)__shfl((int)u, qb + 4);
            g2 = (uint32_t)__shfl((int)u, qb + 8);  g3 = (uint32_t)__shfl((int)u, qb + 12);
            pl2 = (g0 | (g1 << 16)) ^ pm;  ph2 = (g2 | (g3 << 16)) ^ pm;
            u = (uint32_t)f2b(act[3]);
            g0 = (uint32_t)__shfl((int)u, qb + 0);  g1 = (uint32_t)__shfl((int)u, qb + 4);
            g2 = (uint32_t)__shfl((int)u, qb + 8);  g3 = (uint32_t)__shfl((int)u, qb + 12);
            pl3 = (g0 | (g1 << 16)) ^ pm;  ph3 = (g2 | (g3 << 16)) ^ pm;
        }
        // static select by col (cndmask chain; no dynamic reg indexing)
        uint32_t lo = (col == 0) ? pl0 : (col == 1) ? pl1 : (col == 2) ? pl2 : pl3;
        uint32_t hi = (col == 0) ? ph0 : (col == 1) ? ph1 : (col == 2) ? ph2 : ph3;
        if (col < 4) {                         // 16 lanes, contiguous 128B
            u32x2 pk; pk[0] = lo; pk[1] = hi;
            void* p = dst + (q * 4 + col) * 8;
            asm volatile("global_store_dwordx2 %0, %1, off sc0 sc1"
                         :: "v"(p), "v"(pk) : "memory");
        }
    };

    short8 wfrag[16];
    auto load_wfrag_f32 = [&](const float* Wsrc) {
        #pragma unroll
        for (int kt = 0; kt < 16; ++kt)
            wfrag[kt] = cvt8(Wsrc + (size_t)grow * 512 + kt * 32 + q * 8);
    };
    auto load_wfrag_bf16 = [&](const unsigned short* Wsrc) {
        #pragma unroll
        for (int kt = 0; kt < 16; ++kt)
            wfrag[kt] = *(const short8*)((const short*)Wsrc +
                         (size_t)grow * 512 + kt * 32 + q * 8);
    };

    // ---------------- encoder: 512 steps ----------------
    load_wfrag_f32(Whh_e);
    short8 xwf[2];
    #pragma unroll
    for (int kt = 0; kt < 2; ++kt)
        xwf[kt] = cvt8(Wih_e + (size_t)grow * 64 + kt * 32 + q * 8);
    const float bias_e = bih_e[grow] + bhh_e[grow];

    auto load_x = [&](int t, short8* xf) {
        if (seqb) {
            const short* xs = (const short*)seqb + ((size_t)(b0 + col) * 512 + t) * 64 + q * 8;
            xf[0] = *(const short8*)(xs);
            xf[1] = *(const short8*)(xs + 32);
        } else {
            const float* xs = seq + ((size_t)(b0 + col) * 512 + t) * 64 + q * 8;
            xf[0] = cvt8(xs);
            xf[1] = cvt8(xs + 32);
        }
    };

    short8 xf[2];
    load_x(0, xf);
    for (uint32_t t = 0; t < 512; ++t) {
        // x-part first: independent of Al, overlaps the poll
        f32x4 acc = {bias_e, bias_e, bias_e, bias_e};
        acc = __builtin_amdgcn_mfma_f32_16x16x32_bf16(xf[0], xwf[0], acc, 0, 0, 0);
        acc = __builtin_amdgcn_mfma_f32_16x16x32_bf16(xf[1], xwf[1], acc, 0, 0, 0);
        if (t < 511) load_x(t + 1, xf);
        wait_and_stage(t);                   // t=0: hbuf0 zeros, phase 0 -> instant
        const short* ab = Al + (t & 1) * AL_HALF;
        f32x4 acc1 = {0.f, 0.f, 0.f, 0.f};   // 2 chains: halve serial latency
        #pragma unroll
        for (int kt = 0; kt < 16; kt += 2) {
            short8 a0 = ldfrag(ab, kt);
            short8 a1 = ldfrag(ab, kt + 1);
            acc  = __builtin_amdgcn_mfma_f32_16x16x32_bf16(a0, wfrag[kt],     acc,  0, 0, 0);
            acc1 = __builtin_amdgcn_mfma_f32_16x16x32_bf16(a1, wfrag[kt + 1], acc1, 0, 0, 0);
        }
        #pragma unroll
        for (int r = 0; r < 4; ++r) acc[r] += acc1[r];
        cell_publish(acc, t + 1);            // one coalesced store, no barrier
    }

    // ---------------- VAE reparameterization (flag 513 = z ready) ---------
    wait_and_stage(512);                     // Al[0] = h_n (block layout)
    if (tid < 128) {
        int which = tid >> 6, idx = tid & 63;
        int b = idx >> 2, ldl = idx & 3;
        int ld = s * 4 + ldl;
        const float* wrow = (which ? Wlv : Wmean) + (size_t)ld * 512;
        float a = (which ? blv[ld] : bmean[ld]);
        for (int u = 0; u < 128; ++u) {      // block u = dims u*4+{0..3}
            const short* ap = Al + u * 64 + b * 4;
            const float* wp = wrow + u * 4;
            #pragma unroll
            for (int e = 0; e < 4; ++e)
                a += b2f((unsigned short)ap[e]) * wp[e];
        }
        out[819200 + which * 8192 + (size_t)(b0 + b) * 64 + ld] = a;
        fbuf[which * 64 + idx] = a;
    }
    __syncthreads();
    if (wv == 0) {
        int b = lane >> 2, ldl = lane & 3;
        int ld = s * 4 + ldl;
        float m = fbuf[lane], lv = fbuf[64 + lane];
        float e = eps[(size_t)(b0 + b) * 64 + ld];
        float z = m + e * __expf(0.5f * lv);
        __hip_atomic_store(zbuf + (size_t)(b0 + b) * 64 + ld,
                           __builtin_bit_cast(uint32_t, z),
                           __ATOMIC_RELAXED, __HIP_MEMORY_SCOPE_AGENT);
        drain_vm();
        if (lane == 0)
            __hip_atomic_store(&flags[s * 32], 513u,
                               __ATOMIC_RELAXED, __HIP_MEMORY_SCOPE_AGENT);
    }
    if (wv == 0 && lane < 16)
        while (__hip_atomic_load(&flags[lane * 32], __ATOMIC_RELAXED,
                                 __HIP_MEMORY_SCOPE_AGENT) < 513u) {}
    __syncthreads();

    // h_dec0 = z @ W_init^T + b_init -> Al[1] (round-513 parity, block layout)
    #pragma unroll
    for (int j = 0; j < 2; ++j) {
        int idx = tid + j * 512;
        int b = idx >> 6, l = idx & 63;
        uint32_t v = __hip_atomic_load(zbuf + (size_t)(b0 + b) * 64 + l,
                                       __ATOMIC_RELAXED, __HIP_MEMORY_SCOPE_AGENT);
        zl[b * 64 + l] = __builtin_bit_cast(float, v);
    }
    __syncthreads();
    {
        int b = tid >> 5, c = tid & 31;
        #pragma unroll
        for (int j = 0; j < 16; ++j) {
            int hd = c * 16 + j;
            float a = binit[hd];
            const float* wr = Winit + (size_t)hd * 64;
            #pragma unroll
            for (int l = 0; l < 64; ++l) a += zl[b * 64 + l] * wr[l];
            Al[AL_HALF + (hd >> 2) * 64 + b * 4 + (hd & 3)] = (short)f2b(a);
        }
    }
    #pragma unroll
    for (int r = 0; r < 4; ++r) cst[r] = 0.f;
    __syncthreads();

    // -------- decoder: 100 steps; step d publishes h_{d+1} as R=514+d -----
    short8 wof[16];
    float xbias = 0.f;
    if (s < 4 && wv == 7) {                  // x_hat tile s on wave 7 (no duties)
        xbias = bout[s * 16 + col];
        #pragma unroll
        for (int kt = 0; kt < 16; ++kt)
            wof[kt] = cvt8(Wout + (size_t)(s * 16 + col) * 512 + kt * 32 + q * 8);
    }
    auto xhat_emit = [&](int d, const short* ab) {  // x_hat_d from ab (= h_{d+1})
        f32x4 a2 = {xbias, xbias, xbias, xbias};
        #pragma unroll
        for (int kt = 0; kt < 16; ++kt) {
            short8 a = ldfrag(ab, kt);
            a2 = __builtin_amdgcn_mfma_f32_16x16x32_bf16(a, wof[kt], a2, 0, 0, 0);
        }
        #pragma unroll
        for (int r = 0; r < 4; ++r) {
            int b = q * 4 + r;
            out[((size_t)(b0 + b) * 100 + d) * 64 + s * 16 + col] = a2[r];
        }
    };

    load_wfrag_f32(Whh_d);                   // step 0: x0 == 0
    float bias = bih_d[grow] + bhh_d[grow];
    for (uint32_t d = 0; d < 100; ++d) {
        const uint32_t Rin = 513 + d;        // round holding h_d
        if (d > 0) wait_and_stage(Rin);      // Al[Rin&1] = h_d
        const short* ab = Al + (Rin & 1) * AL_HALF;
        f32x4 acc = {bias, bias, bias, bias};
        f32x4 acc1 = {0.f, 0.f, 0.f, 0.f};
        #pragma unroll
        for (int kt = 0; kt < 16; kt += 2) {
            short8 a0 = ldfrag(ab, kt);
            short8 a1 = ldfrag(ab, kt + 1);
            acc  = __builtin_amdgcn_mfma_f32_16x16x32_bf16(a0, wfrag[kt],     acc,  0, 0, 0);
            acc1 = __builtin_amdgcn_mfma_f32_16x16x32_bf16(a1, wfrag[kt + 1], acc1, 0, 0, 0);
        }
        #pragma unroll
        for (int r = 0; r < 4; ++r) acc[r] += acc1[r];
        cell_publish(acc, 514 + d);
        if (d >= 1 && s < 4 && wv == 7) xhat_emit(d - 1, ab);  // opposite parity
        if (d == 0) {                                          // vs next staging
            load_wfrag_bf16((const unsigned short*)(ws + WS_WCOMB));
            bias = ((const float*)(ws + WS_BCOMB))[grow];
        }
    }
    wait_and_stage(613);                     // Al[1] = h_100
    if (s < 4 && wv == 7) xhat_emit(99, Al + AL_HALF);
}

extern "C" void kernel_launch(void* const* d_in, const int* in_sizes, int n_in,
                              void* d_out, int out_size, void* d_ws, size_t ws_size,
                              hipStream_t stream) {
    (void)in_sizes; (void)n_in; (void)out_size;
    const float* seq   = (const float*)d_in[0];
    const float* eps   = (const float*)d_in[2];
    const float* Wih_e = (const float*)d_in[3];
    const float* Whh_e = (const float*)d_in[4];
    const float* bih_e = (const float*)d_in[5];
    const float* bhh_e = (const float*)d_in[6];
    const float* Wmean = (const float*)d_in[7];
    const float* bmean = (const float*)d_in[8];
    const float* Wlv   = (const float*)d_in[9];
    const float* blv   = (const float*)d_in[10];
    const float* Winit = (const float*)d_in[11];
    const float* binit = (const float*)d_in[12];
    const float* Wih_d = (const float*)d_in[13];
    const float* Whh_d = (const float*)d_in[14];
    const float* bih_d = (const float*)d_in[15];
    const float* bhh_d = (const float*)d_in[16];
    const float* Wout  = (const float*)d_in[17];
    const float* bout  = (const float*)d_in[18];
    unsigned char* ws = (unsigned char*)d_ws;
    float* out = (float*)d_out;

    const bool have_seqb = ws_size >= (size_t)WS_END;
    unsigned short* seqb = have_seqb ? (unsigned short*)(ws + WS_SEQB) : nullptr;

    hipMemsetAsync(ws, 0, WS_ZERO, stream);            // flags + hbuf0 (phase 0)
    hipMemsetAsync(ws + WS_HBUF1, 0x40, HB1_SIZE, stream);  // hbuf1: bit14=1
    if (have_seqb)
        seqcvt_kernel<<<4096, 256, 0, stream>>>(seq, seqb);
    wcomb_kernel<<<256, 256, 0, stream>>>(Wih_d, Whh_d, Wout, bih_d, bhh_d, bout, ws);
    vae_persistent<<<128, 512, 0, stream>>>(
        seq, seqb, eps, Wih_e, Whh_e, bih_e, bhh_e,
        Wmean, bmean, Wlv, blv, Winit, binit,
        Whh_d, bih_d, bhh_d, Wout, bout, ws, out);
}

// Round 12
// 1762.268 us; speedup vs baseline: 1.8766x; 1.3496x over previous
//
#include <hip/hip_runtime.h>
#include <stdint.h>

// ---------------------------------------------------------------------------
// LSTM-VAE persistent kernel, MI355X (gfx950).  B=128, T=512, I=L=64, H=512,
// 100 decoder steps.  fp32 in/out; bf16 MFMA internal.
//
// 128 WGs = 8 batch-groups(g) x 16 hidden-slices(s), block=512 (8 waves).
// Slice owns 32 hidden dims = 128 interleaved gate rows [i0,f0,g0,o0,...];
// W_hh slice in 64 VGPRs/lane as MFMA B-fragments. Decoder folds x_hat via
// W_comb = W_hh_dec + W_ih_dec@W_out; x_hat tiles on wave 7 of slices 0-3.
//
// Round-20: REVERT to the green r14 skeleton (1664us proven; the r16-r19
// one-barrier/per-wave-publish line peaked at 2311 despite clean WRITE
// and 4x fewer bank conflicts -- condemned).  ONE change vs r14:
//   RETRY POLICY.  r19's FETCH analysis: sc0sc1 stores are write-through/
//   no-allocate; the FIRST reader of each line pays an HBM miss (shows in
//   FETCH exactly once per byte), later readers + all retries hit LLC
//   (invisible in FETCH).  So the ~1.5us/step of non-compute time is
//   retry cost: each retry = full synchronous 32B reload (~350-600cy)
//   PLUS backoff sleep (64-512cy quantization).  New policy: first two
//   retries hot (no sleep -> detect within one load-RT of readiness),
//   then constant s_sleep(1).  Not r9's disaster: only missing lanes
//   reload (per-lane exec), steady-state traffic ~1.5TB/s << LLC
//   capability; deep 512cy sleeps (DVFS-outlier bait) are gone.
//
// Sync: POLL-ON-DATA phase-bit protocol (r9/r10/r14, HW-verified).
// |h|<=1 so bit14 of every bf16 is 0.  Round R writes buf[R&1] with each
// bf16 XOR'd by (phase(R) ? 0x4000 : 0); phase alternates on every reuse
// of a buffer.  Consumers poll their own 32B chunk until EVERY bf16
// carries the round's phase bit (stores are dword-atomic; torn arrival
// keeps polling; stale phase is always the complement).  One-shot first
// load + miss-only retries.  Overwrite safety: depth-2 transitive
// certification (publishing R+1 follows staging R).  Round 513 (h_dec0)
// is computed locally -> decoder rounds >=514 use a shifted phase
// formula.  hbuf1 pre-filled 0x40 so round 1 (phase 0) cannot
// false-trigger.  Flags kept only for the one-shot fp32 z exchange.
// All coherent ops are the proven `sc0 sc1` (LLC) path; monolithic
// load+waitcnt with "=&v" early-clobber (r15 crash lesson).
// ---------------------------------------------------------------------------

typedef short short8 __attribute__((ext_vector_type(8)));
typedef float f32x4 __attribute__((ext_vector_type(4)));
typedef unsigned int u32x4 __attribute__((ext_vector_type(4)));

#define WS_FLAGS  0           // 8 g x 16 s x 128 B (z exchange only)
#define WS_HBUF0  16384       // 128 KB
#define WS_HBUF1  147456      // 128 KB
#define WS_Z      278528      // 32 KB fp32
#define WS_BCOMB  311296      // 8 KB fp32
#define WS_WCOMB  319488      // 2 MB bf16
#define WS_SEQB   2416640     // 8 MB bf16 seq
#define WS_END    10805248
#define WS_ZERO   WS_HBUF1    // memset flags + hbuf0 (h0 = 0, phase 0)
#define HB1_SIZE  131072      // hbuf1: fill 0x40 (bit14=1, != phase 0)

static __device__ __forceinline__ float b2f(unsigned short u) {
    return __builtin_bit_cast(float, (unsigned int)u << 16);
}
static __device__ __forceinline__ unsigned short f2b(float f) {
    unsigned int u = __builtin_bit_cast(unsigned int, f);
    unsigned int r = u + 0x7FFFu + ((u >> 16) & 1u);  // RNE
    return (unsigned short)(r >> 16);
}
static __device__ __forceinline__ float sigm(float x)  { return 1.0f / (1.0f + __expf(-x)); }
static __device__ __forceinline__ float tanhx(float x) { return 1.0f - 2.0f / (__expf(2.0f * x) + 1.0f); }

static __device__ __forceinline__ short8 cvt8(const float* p) {
    const float4 a = ((const float4*)p)[0];
    const float4 b = ((const float4*)p)[1];
    short8 r;
    r[0] = (short)f2b(a.x); r[1] = (short)f2b(a.y);
    r[2] = (short)f2b(a.z); r[3] = (short)f2b(a.w);
    r[4] = (short)f2b(b.x); r[5] = (short)f2b(b.y);
    r[6] = (short)f2b(b.z); r[7] = (short)f2b(b.w);
    return r;
}

// phase(R): encoder/VAE rounds 0..512: (R>>1)&1.  Round 513 skipped (local
// h_dec0).  Decoder rounds 514..613 shifted so every buffer reuse still
// alternates (buf0: 512(0),514(1),516(0)..; buf1: 511(1),515(0),517(1)..).
static __device__ __forceinline__ uint32_t phase_of(uint32_t R) {
    return (R <= 512u) ? ((R >> 1) & 1u)
                       : ((((R - 513u) >> 1) & 1u) ^ 1u);
}

// LDS bank swizzle for the Al tile: 16B unit u of a row is stored at
// alperm(u).  Bijective; spreads the 8 lanes that used to share a 4-bank
// group across all 8 groups.
static __device__ __forceinline__ int alperm(int u) { return u ^ ((u >> 3) & 7); }

// --- coherent (LLC-served, L1/L2-bypass) coalesced ops: sc0 sc1 ----------
static __device__ __forceinline__ void load2x16_cc(const void* p0, const void* p1,
                                                   u32x4& v0, u32x4& v1) {
    asm volatile("global_load_dwordx4 %0, %2, off sc0 sc1\n\t"
                 "global_load_dwordx4 %1, %3, off sc0 sc1\n\t"
                 "s_waitcnt vmcnt(0)"
                 : "=&v"(v0), "=&v"(v1) : "v"(p0), "v"(p1) : "memory");
}
static __device__ __forceinline__ void store16_cc(void* p, u32x4 v) {
    asm volatile("global_store_dwordx4 %0, %1, off sc0 sc1"
                 :: "v"(p), "v"(v) : "memory");
}
static __device__ __forceinline__ void drain_vm() {
    asm volatile("s_waitcnt vmcnt(0)" ::: "memory");
}

// ---------------------------------------------------------------------------
// Prologue A: seq fp32 -> bf16
// ---------------------------------------------------------------------------
__global__ void __launch_bounds__(256)
seqcvt_kernel(const float* __restrict__ src, unsigned short* __restrict__ dst)
{
    int i = (blockIdx.x * 256 + threadIdx.x) * 4;
    float4 v = *(const float4*)(src + i);
    uint32_t lo = (uint32_t)f2b(v.x) | ((uint32_t)f2b(v.y) << 16);
    uint32_t hi = (uint32_t)f2b(v.z) | ((uint32_t)f2b(v.w) << 16);
    uint2 o; o.x = lo; o.y = hi;
    *(uint2*)(dst + i) = o;
}

// ---------------------------------------------------------------------------
// Prologue B: W_comb = W_hh_dec + W_ih_dec @ W_out (bf16 out), b_comb (fp32)
// ---------------------------------------------------------------------------
__global__ void __launch_bounds__(256)
wcomb_kernel(const float* __restrict__ Wih_d,
             const float* __restrict__ Whh_d,
             const float* __restrict__ Wout,
             const float* __restrict__ bih_d,
             const float* __restrict__ bhh_d,
             const float* __restrict__ bout,
             unsigned char* __restrict__ ws)
{
    __shared__ float Ash[64][64];
    __shared__ float Bsh[64][65];
    const int bid = blockIdx.x, t = threadIdx.x;
    const int gt0 = (bid >> 3) * 64, ht0 = (bid & 7) * 64;
    for (int j = 0; j < 16; ++j) {
        int idx = t + j * 256;
        int r = idx >> 6, c = idx & 63;
        Ash[r][c] = Wih_d[(size_t)(gt0 + r) * 64 + c];
        Bsh[r][c] = Wout[(size_t)r * 512 + ht0 + c];
    }
    __syncthreads();
    const int gl = t >> 2, hl0 = (t & 3) * 16;
    for (int hh = 0; hh < 16; ++hh) {
        float acc = 0.f;
        #pragma unroll
        for (int i = 0; i < 64; ++i) acc += Ash[gl][i] * Bsh[i][hl0 + hh];
        int g = gt0 + gl, h = ht0 + hl0 + hh;
        float v = Whh_d[(size_t)g * 512 + h] + acc;
        ((unsigned short*)(ws + WS_WCOMB))[(size_t)g * 512 + h] = f2b(v);
    }
    if ((bid & 7) == 0 && t < 64) {
        int g = gt0 + t;
        float acc = bih_d[g] + bhh_d[g];
        #pragma unroll
        for (int i = 0; i < 64; ++i) acc += bout[i] * Ash[t][i];
        ((float*)(ws + WS_BCOMB))[g] = acc;
    }
}

// ---------------------------------------------------------------------------
// Main persistent kernel
// ---------------------------------------------------------------------------
__global__ void __launch_bounds__(512, 2)
vae_persistent(const float* __restrict__ seq,
               const unsigned short* __restrict__ seqb,
               const float* __restrict__ eps,
               const float* __restrict__ Wih_e,
               const float* __restrict__ Whh_e,
               const float* __restrict__ bih_e,
               const float* __restrict__ bhh_e,
               const float* __restrict__ Wmean,
               const float* __restrict__ bmean,
               const float* __restrict__ Wlv,
               const float* __restrict__ blv,
               const float* __restrict__ Winit,
               const float* __restrict__ binit,
               const float* __restrict__ Whh_d,
               const float* __restrict__ bih_d,
               const float* __restrict__ bhh_d,
               const float* __restrict__ Wout,
               const float* __restrict__ bout,
               unsigned char* __restrict__ ws,
               float* __restrict__ out)
{
    __shared__ __align__(16) short Al[16 * 520];  // staged h tile (bf16, bank-swizzled)
    __shared__ __align__(16) short Ho[16 * 36];   // h write-back staging, stride 36
    __shared__ float fbuf[128];                   // mean/logvar scratch
    __shared__ float zl[16 * 64];                 // z tile (fp32)

    const int tid  = threadIdx.x;
    const int g    = blockIdx.x & 7;        // batch group
    const int s    = blockIdx.x >> 3;       // hidden slice
    const int b0   = g * 16;
    const int lane = tid & 63;
    const int wv   = tid >> 6;
    const int col  = lane & 15;
    const int q    = lane >> 4;
    const int nloc = wv * 16 + col;
    const int gt   = nloc & 3;              // 0=i,1=f,2=g,3=o
    const int grow = gt * 512 + s * 32 + (nloc >> 2);

    uint32_t* flags = (uint32_t*)(ws + WS_FLAGS) + (size_t)g * 512;  // z only
    unsigned char* hbuf0 = ws + WS_HBUF0;
    unsigned char* hbuf1 = ws + WS_HBUF1;
    uint32_t* zbuf = (uint32_t*)(ws + WS_Z);

    float cst[4] = {0.f, 0.f, 0.f, 0.f};

    // Per-thread swizzled LDS offsets (all consumers fully unrolled -> VGPRs)
    int aoff[16];
    #pragma unroll
    for (int kt = 0; kt < 16; ++kt)
        aoff[kt] = col * 520 + alperm(kt * 4 + q) * 8;   // short index
    const int stg_b  = tid >> 5;                          // staged row
    const int stg_c  = tid & 31;                          // 32B chunk
    const int stg_u0 = alperm(stg_c * 2);                 // unit of first 16B
    // second 16B unit is stg_u0 ^ 1

    // ---- stage round R: one-shot load, hot-then-trickle retry ------------
    auto wait_and_stage = [&](uint32_t R, bool guard) {
        if (guard) __syncthreads();            // decoder: xhat still reads Al
        const unsigned char* src = (R & 1) ? hbuf1 : hbuf0;
        const uint32_t pm = phase_of(R) ? 0x40004000u : 0u;
        const unsigned char* p0 = src + (size_t)(b0 + stg_b) * 1024 + stg_c * 32;
        u32x4 v0, v1;
        uint32_t tries = 0;
        for (;;) {
            load2x16_cc(p0, p0 + 16, v0, v1);
            uint32_t bad = 0;
            #pragma unroll
            for (int i = 0; i < 4; ++i) {
                bad |= (v0[i] & 0x40004000u) ^ pm;
                bad |= (v1[i] & 0x40004000u) ^ pm;
            }
            if (bad == 0) break;               // per-lane exit
            // r20 policy: first two retries hot (detect at load-RT
            // granularity); steady trickle s_sleep(1) after that.
            if (tries >= 2) __builtin_amdgcn_s_sleep(1);
            ++tries;
        }
        #pragma unroll
        for (int i = 0; i < 4; ++i) { v0[i] ^= pm; v1[i] ^= pm; }
        u32x4* dst = (u32x4*)Al;               // row stride 65 units (520 shorts)
        dst[stg_b * 65 + stg_u0]       = v0;
        dst[stg_b * 65 + (stg_u0 ^ 1)] = v1;
        __syncthreads();
    };

    // ---- publish round R (wave 0: phase-tagged stores, NO drain/flag) ----
    auto publish_h = [&](uint32_t R) {
        if (wv == 0) {
            unsigned char* dst = (R & 1) ? hbuf1 : hbuf0;
            const uint32_t pm = phase_of(R) ? 0x40004000u : 0u;
            int row = lane >> 2, part = lane & 3;          // 16 B per lane
            const short* hp = Ho + row * 36 + part * 8;
            uint2 lo = *(const uint2*)(hp);
            uint2 hi = *(const uint2*)(hp + 4);
            u32x4 v; v[0] = lo.x; v[1] = lo.y; v[2] = hi.x; v[3] = hi.y;
            #pragma unroll
            for (int i = 0; i < 4; ++i) v[i] ^= pm;
            store16_cc(dst + (size_t)(b0 + row) * 1024 + s * 64 + part * 16, v);
        }
    };

    short8 wfrag[16];
    auto load_wfrag_f32 = [&](const float* Wsrc) {
        #pragma unroll
        for (int kt = 0; kt < 16; ++kt)
            wfrag[kt] = cvt8(Wsrc + (size_t)grow * 512 + kt * 32 + q * 8);
    };
    auto load_wfrag_bf16 = [&](const unsigned short* Wsrc) {
        #pragma unroll
        for (int kt = 0; kt < 16; ++kt)
            wfrag[kt] = *(const short8*)((const short*)Wsrc +
                         (size_t)grow * 512 + kt * 32 + q * 8);
    };

    // activations + cell update; h slice left in Ho (sync before publish)
    auto cell_update = [&](f32x4 acc) {
        float act[4];
        #pragma unroll
        for (int r = 0; r < 4; ++r)
            act[r] = (gt == 2) ? tanhx(acc[r]) : sigm(acc[r]);
        int base = lane & ~3;
        #pragma unroll
        for (int r = 0; r < 4; ++r) {
            float vi = __shfl(act[r], base + 0);
            float vf = __shfl(act[r], base + 1);
            float vg = __shfl(act[r], base + 2);
            float vo = __shfl(act[r], base + 3);
            cst[r] = vf * cst[r] + vi * vg;
            act[r] = vo * tanhx(cst[r]);
        }
        if (gt == 0) {
            int hd4 = wv * 4 + (col >> 2);     // 0..31
            #pragma unroll
            for (int r = 0; r < 4; ++r)
                Ho[(q * 4 + r) * 36 + hd4] = (short)f2b(act[r]);
        }
    };

    // ---------------- encoder: 512 steps ----------------
    load_wfrag_f32(Whh_e);
    short8 xwf[2];
    #pragma unroll
    for (int kt = 0; kt < 2; ++kt)
        xwf[kt] = cvt8(Wih_e + (size_t)grow * 64 + kt * 32 + q * 8);
    const float bias_e = bih_e[grow] + bhh_e[grow];

    auto load_x = [&](int t, short8* xf) {
        if (seqb) {
            const short* xs = (const short*)seqb + ((size_t)(b0 + col) * 512 + t) * 64 + q * 8;
            xf[0] = *(const short8*)(xs);
            xf[1] = *(const short8*)(xs + 32);
        } else {
            const float* xs = seq + ((size_t)(b0 + col) * 512 + t) * 64 + q * 8;
            xf[0] = cvt8(xs);
            xf[1] = cvt8(xs + 32);
        }
    };

    short8 xf[2];
    load_x(0, xf);
    for (uint32_t t = 0; t < 512; ++t) {
        // x-part first: independent of Al, overlaps the poll
        f32x4 acc = {bias_e, bias_e, bias_e, bias_e};
        acc = __builtin_amdgcn_mfma_f32_16x16x32_bf16(xf[0], xwf[0], acc, 0, 0, 0);
        acc = __builtin_amdgcn_mfma_f32_16x16x32_bf16(xf[1], xwf[1], acc, 0, 0, 0);
        if (t < 511) load_x(t + 1, xf);
        wait_and_stage(t, false);            // t=0: hbuf0 zeros, phase 0 -> instant
        f32x4 acc1 = {0.f, 0.f, 0.f, 0.f};   // 2 chains: halve serial MFMA latency
        #pragma unroll
        for (int kt = 0; kt < 16; kt += 2) {
            short8 a0 = *(const short8*)(Al + aoff[kt]);
            short8 a1 = *(const short8*)(Al + aoff[kt + 1]);
            acc  = __builtin_amdgcn_mfma_f32_16x16x32_bf16(a0, wfrag[kt],     acc,  0, 0, 0);
            acc1 = __builtin_amdgcn_mfma_f32_16x16x32_bf16(a1, wfrag[kt + 1], acc1, 0, 0, 0);
        }
        #pragma unroll
        for (int r = 0; r < 4; ++r) acc[r] += acc1[r];
        cell_update(acc);
        __syncthreads();
        publish_h(t + 1);                    // h_{t+1} -> round t+1
    }

    // ---------------- VAE reparameterization (flag 513 = z ready) ---------
    wait_and_stage(512, false);              // Al = h_n
    if (tid < 128) {
        int which = tid >> 6, idx = tid & 63;
        int b = idx >> 2, ldl = idx & 3;
        int ld = s * 4 + ldl;
        const float* wrow = (which ? Wlv : Wmean) + (size_t)ld * 512;
        float a = (which ? blv[ld] : bmean[ld]);
        for (int u = 0; u < 64; ++u) {
            const short* ap = Al + b * 520 + alperm(u) * 8;
            const float* wp = wrow + u * 8;
            #pragma unroll
            for (int e = 0; e < 8; ++e)
                a += b2f((unsigned short)ap[e]) * wp[e];
        }
        out[819200 + which * 8192 + (size_t)(b0 + b) * 64 + ld] = a;
        fbuf[which * 64 + idx] = a;
    }
    __syncthreads();
    if (wv == 0) {
        int b = lane >> 2, ldl = lane & 3;
        int ld = s * 4 + ldl;
        float m = fbuf[lane], lv = fbuf[64 + lane];
        float e = eps[(size_t)(b0 + b) * 64 + ld];
        float z = m + e * __expf(0.5f * lv);
        __hip_atomic_store(zbuf + (size_t)(b0 + b) * 64 + ld,
                           __builtin_bit_cast(uint32_t, z),
                           __ATOMIC_RELAXED, __HIP_MEMORY_SCOPE_AGENT);
        drain_vm();
        if (lane == 0)
            __hip_atomic_store(&flags[s * 32], 513u,
                               __ATOMIC_RELAXED, __HIP_MEMORY_SCOPE_AGENT);
    }
    if (wv == 0 && lane < 16)
        while (__hip_atomic_load(&flags[lane * 32], __ATOMIC_RELAXED,
                                 __HIP_MEMORY_SCOPE_AGENT) < 513u) {}
    __syncthreads();

    // h_dec0 = z @ W_init^T + b_init, computed locally into Al (swizzled)
    #pragma unroll
    for (int j = 0; j < 2; ++j) {
        int idx = tid + j * 512;
        int b = idx >> 6, l = idx & 63;
        uint32_t v = __hip_atomic_load(zbuf + (size_t)(b0 + b) * 64 + l,
                                       __ATOMIC_RELAXED, __HIP_MEMORY_SCOPE_AGENT);
        zl[b * 64 + l] = __builtin_bit_cast(float, v);
    }
    __syncthreads();
    {
        int b = tid >> 5, c = tid & 31;
        #pragma unroll
        for (int j = 0; j < 16; ++j) {
            int hd = c * 16 + j;
            float a = binit[hd];
            const float* wr = Winit + (size_t)hd * 64;
            #pragma unroll
            for (int l = 0; l < 64; ++l) a += zl[b * 64 + l] * wr[l];
            Al[b * 520 + alperm(c * 2 + (j >> 3)) * 8 + (j & 7)] = (short)f2b(a);
        }
    }
    #pragma unroll
    for (int r = 0; r < 4; ++r) cst[r] = 0.f;
    __syncthreads();

    // -------- decoder: 100 steps; step d publishes h_{d+1} as R=514+d -----
    short8 wof[16];
    float xbias = 0.f;
    if (s < 4 && wv == 7) {                  // x_hat tile s on wave 7 (no duties)
        xbias = bout[s * 16 + col];
        #pragma unroll
        for (int kt = 0; kt < 16; ++kt)
            wof[kt] = cvt8(Wout + (size_t)(s * 16 + col) * 512 + kt * 32 + q * 8);
    }
    auto xhat_emit = [&](int d) {            // x_hat_d from Al (= h_{d+1})
        f32x4 a2 = {xbias, xbias, xbias, xbias};
        #pragma unroll
        for (int kt = 0; kt < 16; ++kt) {
            short8 a = *(const short8*)(Al + aoff[kt]);
            a2 = __builtin_amdgcn_mfma_f32_16x16x32_bf16(a, wof[kt], a2, 0, 0, 0);
        }
        #pragma unroll
        for (int r = 0; r < 4; ++r) {
            int b = q * 4 + r;
            out[((size_t)(b0 + b) * 100 + d) * 64 + s * 16 + col] = a2[r];
        }
    };

    load_wfrag_f32(Whh_d);                   // step 0: x0 == 0
    float bias = bih_d[grow] + bhh_d[grow];
    for (uint32_t d = 0; d < 100; ++d) {
        if (d > 0) wait_and_stage(513 + d, true);  // Al = h_d
        f32x4 acc = {bias, bias, bias, bias};
        f32x4 acc1 = {0.f, 0.f, 0.f, 0.f};
        #pragma unroll
        for (int kt = 0; kt < 16; kt += 2) {
            short8 a0 = *(const short8*)(Al + aoff[kt]);
            short8 a1 = *(const short8*)(Al + aoff[kt + 1]);
            acc  = __builtin_amdgcn_mfma_f32_16x16x32_bf16(a0, wfrag[kt],     acc,  0, 0, 0);
            acc1 = __builtin_amdgcn_mfma_f32_16x16x32_bf16(a1, wfrag[kt + 1], acc1, 0, 0, 0);
        }
        #pragma unroll
        for (int r = 0; r < 4; ++r) acc[r] += acc1[r];
        cell_update(acc);
        __syncthreads();
        publish_h(514 + d);
        if (d >= 1 && s < 4 && wv == 7) xhat_emit(d - 1);   // off critical path
        if (d == 0) {
            load_wfrag_bf16((const unsigned short*)(ws + WS_WCOMB));
            bias = ((const float*)(ws + WS_BCOMB))[grow];
        }
    }
    wait_and_stage(613, true);               // Al = h_100
    if (s < 4 && wv == 7) xhat_emit(99);
}

extern "C" void kernel_launch(void* const* d_in, const int* in_sizes, int n_in,
                              void* d_out, int out_size, void* d_ws, size_t ws_size,
                              hipStream_t stream) {
    (void)in_sizes; (void)n_in; (void)out_size;
    const float* seq   = (const float*)d_in[0];
    const float* eps   = (const float*)d_in[2];
    const float* Wih_e = (const float*)d_in[3];
    const float* Whh_e = (const float*)d_in[4];
    const float* bih_e = (const float*)d_in[5];
    const float* bhh_e = (const float*)d_in[6];
    const float* Wmean = (const float*)d_in[7];
    const float* bmean = (const float*)d_in[8];
    const float* Wlv   = (const float*)d_in[9];
    const float* blv   = (const float*)d_in[10];
    const float* Winit = (const float*)d_in[11];
    const float* binit = (const float*)d_in[12];
    const float* Wih_d = (const float*)d_in[13];
    const float* Whh_d = (const float*)d_in[14];
    const float* bih_d = (const float*)d_in[15];
    const float* bhh_d = (const float*)d_in[16];
    const float* Wout  = (const float*)d_in[17];
    const float* bout  = (const float*)d_in[18];
    unsigned char* ws = (unsigned char*)d_ws;
    float* out = (float*)d_out;

    const bool have_seqb = ws_size >= (size_t)WS_END;
    unsigned short* seqb = have_seqb ? (unsigned short*)(ws + WS_SEQB) : nullptr;

    hipMemsetAsync(ws, 0, WS_ZERO, stream);            // flags + hbuf0 (phase 0)
    hipMemsetAsync(ws + WS_HBUF1, 0x40, HB1_SIZE, stream);  // hbuf1: bit14=1
    if (have_seqb)
        seqcvt_kernel<<<4096, 256, 0, stream>>>(seq, seqb);
    wcomb_kernel<<<256, 256, 0, stream>>>(Wih_d, Whh_d, Wout, bih_d, bhh_d, bout, ws);
    vae_persistent<<<128, 512, 0, stream>>>(
        seq, seqb, eps, Wih_e, Whh_e, bih_e, bhh_e,
        Wmean, bmean, Wlv, blv, Winit, binit,
        Whh_d, bih_d, bhh_d, Wout, bout, ws, out);
}